// Round 6
// baseline (271.335 us; speedup 1.0000x reference)
//
#include <hip/hip_runtime.h>
#include <hip/hip_bf16.h>

typedef __attribute__((ext_vector_type(8))) short bf16x8;
typedef __attribute__((ext_vector_type(4))) float f32x4;

#define L_SEQ 2048
#define NHEAD 8
#define DHEAD 64
#define DMODEL 512
// split-K chunking: 8 k-steps (512 keys) per block; 40 chunk-slots total
#define NCHUNK 40

__device__ __forceinline__ short f2bf(float f) {
    union { float f; unsigned u; } x; x.f = f;
    unsigned r = x.u + 0x7FFFu + ((x.u >> 16) & 1u);
    return (short)(r >> 16);
}

__device__ __forceinline__ void split1(float x, short& hi, short& lo) {
    unsigned uh = __float_as_uint(x) & 0xFFFF0000u;
    hi = (short)(uh >> 16);
    lo = f2bf(x - __uint_as_float(uh));
}

__device__ __forceinline__ void split8(const float* p, bf16x8& hi, bf16x8& lo) {
    #pragma unroll
    for (int i = 0; i < 8; ++i) {
        float x = p[i];
        unsigned uh = __float_as_uint(x) & 0xFFFF0000u;
        hi[i] = (short)(uh >> 16);
        lo[i] = f2bf(x - __uint_as_float(uh));
    }
}

// ---------------------------------------------------------------------------
// Kernel 1: C = y @ W^T with split-bf16 3-term MFMA (near-f32 accuracy).
//   mode 0 (Wq): q=softplus(C); Qh/Ql[nh][l][0..63]=split(q*cf*cos p),
//                               Qh/Ql[nh][l][64..127]=split(q*cf*sin p)
//   mode 1 (Wk): k=softplus(C); Kh/Kl likewise (cf=1)
//   mode 2 (Wv): Vh/Vl[nh][d][l] = split(C)  (LDS transpose)
// Block: 128 rows x 64 cols (one head), 4 waves. Grid (32, 8, 3).
// ---------------------------------------------------------------------------
__global__ __launch_bounds__(256) void prep_kernel(
    const float* __restrict__ y, const float* __restrict__ positions,
    const float* __restrict__ Wq, const float* __restrict__ Wk, const float* __restrict__ Wv,
    const float* __restrict__ coeff, const float* __restrict__ pw, const float* __restrict__ pb,
    short* __restrict__ Qh, short* __restrict__ Ql,
    short* __restrict__ Kh, short* __restrict__ Kl,
    short* __restrict__ Vh, short* __restrict__ Vl)
{
    __shared__ float vtile[128][65];
    const int mode = blockIdx.z;
    const float* W = (mode == 0) ? Wq : (mode == 1) ? Wk : Wv;
    const int m_base = blockIdx.x * 128;
    const int h = blockIdx.y;
    const int n_base = h * 64;
    const int tid = threadIdx.x;
    const int lane = tid & 63;
    const int wv = tid >> 6;
    const int lr = lane & 15;
    const int lg = lane >> 4;

    f32x4 acc[2][4];
    #pragma unroll
    for (int t = 0; t < 2; ++t)
        #pragma unroll
        for (int c = 0; c < 4; ++c) acc[t][c] = (f32x4){0.f, 0.f, 0.f, 0.f};

    for (int kk = 0; kk < DMODEL; kk += 32) {
        bf16x8 ah[2], al[2], bh[4], bl[4];
        #pragma unroll
        for (int t = 0; t < 2; ++t) {
            const float* src = y + (size_t)(m_base + wv*32 + t*16 + lr) * DMODEL + kk + lg*8;
            float tmp[8];
            *(float4*)tmp       = *(const float4*)src;
            *(float4*)(tmp + 4) = *(const float4*)(src + 4);
            split8(tmp, ah[t], al[t]);
        }
        #pragma unroll
        for (int c = 0; c < 4; ++c) {
            const float* src = W + (size_t)(n_base + c*16 + lr) * DMODEL + kk + lg*8;
            float tmp[8];
            *(float4*)tmp       = *(const float4*)src;
            *(float4*)(tmp + 4) = *(const float4*)(src + 4);
            split8(tmp, bh[c], bl[c]);
        }
        #pragma unroll
        for (int t = 0; t < 2; ++t)
            #pragma unroll
            for (int c = 0; c < 4; ++c) {
                acc[t][c] = __builtin_amdgcn_mfma_f32_16x16x32_bf16(ah[t], bh[c], acc[t][c], 0, 0, 0);
                acc[t][c] = __builtin_amdgcn_mfma_f32_16x16x32_bf16(ah[t], bl[c], acc[t][c], 0, 0, 0);
                acc[t][c] = __builtin_amdgcn_mfma_f32_16x16x32_bf16(al[t], bh[c], acc[t][c], 0, 0, 0);
            }
    }

    if (mode == 2) {
        #pragma unroll
        for (int t = 0; t < 2; ++t)
            #pragma unroll
            for (int c = 0; c < 4; ++c)
                #pragma unroll
                for (int r = 0; r < 4; ++r)
                    vtile[wv*32 + t*16 + lg*4 + r][c*16 + lr] = acc[t][c][r];
        __syncthreads();
        const int d  = tid >> 2;
        const int l0 = (tid & 3) * 32;
        const int n_idx  = m_base >> 11;
        const int l_glob = (m_base & (L_SEQ - 1)) + l0;
        const int nh = n_idx * NHEAD + h;
        const size_t dbase = ((size_t)nh * DHEAD + d) * L_SEQ + l_glob;
        #pragma unroll
        for (int i = 0; i < 4; ++i) {
            bf16x8 ph, pl;
            #pragma unroll
            for (int j = 0; j < 8; ++j) {
                short th, tl;
                split1(vtile[l0 + i*8 + j][d], th, tl);
                ph[j] = th;
                pl[j] = tl;
            }
            *(bf16x8*)(Vh + dbase + i*8) = ph;
            *(bf16x8*)(Vl + dbase + i*8) = pl;
        }
    } else {
        short* OUTh = (mode == 0) ? Qh : Kh;
        short* OUTl = (mode == 0) ? Ql : Kl;
        #pragma unroll
        for (int t = 0; t < 2; ++t) {
            #pragma unroll
            for (int c = 0; c < 4; ++c) {
                const int d = c*16 + lr;
                const float pwv = pw[n_base + d];
                const float pbv = pb[n_base + d];
                const float cf  = (mode == 0) ? coeff[n_base + d] : 1.0f;
                #pragma unroll
                for (int r = 0; r < 4; ++r) {
                    const int gm = m_base + wv*32 + t*16 + lg*4 + r;
                    const int n_idx = gm >> 11;
                    const int l = gm & (L_SEQ - 1);
                    const float posv = positions[gm];
                    const float x = acc[t][c][r];
                    const float sp = fmaxf(x, 0.f) + __logf(1.f + __expf(-fabsf(x)));
                    const float p = pwv * posv + pbv;
                    const float cs = __cosf(p), sn = __sinf(p);
                    const int nh = n_idx * NHEAD + h;
                    const size_t base = ((size_t)nh * L_SEQ + l) * 128;
                    short h1, l1, h2, l2;
                    split1(sp * cf * cs, h1, l1);
                    split1(sp * cf * sn, h2, l2);
                    OUTh[base + d]      = h1;
                    OUTl[base + d]      = l1;
                    OUTh[base + 64 + d] = h2;
                    OUTl[base + 64 + d] = l2;
                }
            }
        }
    }
}

// ---------------------------------------------------------------------------
// Kernel 2: split-K causal attention chunk. Each block = chunk slot cs
// (-> qt, ci) x nh: 128 q rows, up to 8 k-steps of 64 keys. Partial O /
// rowsum written to per-slot slabs (NO atomics — R5 showed the 9.4M-atomic
// epilogue dominated: WRITE 39MB, MfmaUtil 9%). Grid (40, 16), 4 waves.
// ---------------------------------------------------------------------------
__global__ __launch_bounds__(256) void attn_kernel(
    const short* __restrict__ Qh, const short* __restrict__ Ql,
    const short* __restrict__ Kh, const short* __restrict__ Kl,
    const short* __restrict__ Vh, const short* __restrict__ Vl,
    float* __restrict__ O_part, float* __restrict__ rs_part)
{
    __shared__ char s_lds[128 * 256];   // 128 rows x 64 f32, XOR-swizzled
    // map blockIdx.x (chunk slot) -> (qt, chunk index)
    int rem = blockIdx.x, qt = 0;
    for (qt = 0; qt < 16; ++qt) {
        const int nch = (2*qt + 2 + 7) >> 3;
        if (rem < nch) break;
        rem -= nch;
    }
    const int nst = 2*qt + 2;
    const int kt0 = rem * 8;
    const int kt1 = (kt0 + 8 < nst) ? (kt0 + 8) : nst;

    const int nh = blockIdx.y;
    const int q_base = qt * 128;
    const int tid = threadIdx.x;
    const int lane = tid & 63;
    const int wv = tid >> 6;
    const int lr = lane & 15;
    const int lg = lane >> 4;

    const short* Qh_b = Qh + (size_t)nh * L_SEQ * 128;
    const short* Ql_b = Ql + (size_t)nh * L_SEQ * 128;
    const short* Kh_b = Kh + (size_t)nh * L_SEQ * 128;
    const short* Kl_b = Kl + (size_t)nh * L_SEQ * 128;
    const short* Vh_b = Vh + (size_t)nh * DHEAD * L_SEQ;
    const short* Vl_b = Vl + (size_t)nh * DHEAD * L_SEQ;

    bf16x8 qhf[2][4], qlf[2][4];
    #pragma unroll
    for (int t = 0; t < 2; ++t)
        #pragma unroll
        for (int kh = 0; kh < 4; ++kh) {
            const size_t off = (size_t)(q_base + wv*32 + t*16 + lr) * 128 + kh*32 + lg*8;
            qhf[t][kh] = *(const bf16x8*)(Qh_b + off);
            qlf[t][kh] = *(const bf16x8*)(Ql_b + off);
        }

    f32x4 o_acc[2][4];
    float rsum[2][4];
    #pragma unroll
    for (int t = 0; t < 2; ++t) {
        #pragma unroll
        for (int c = 0; c < 4; ++c) o_acc[t][c] = (f32x4){0.f, 0.f, 0.f, 0.f};
        #pragma unroll
        for (int r = 0; r < 4; ++r) rsum[t][r] = 0.f;
    }

    for (int kt = kt0; kt < kt1; ++kt) {
        const int k0 = kt * 64;

        f32x4 s[2][4];
        #pragma unroll
        for (int t = 0; t < 2; ++t)
            #pragma unroll
            for (int c = 0; c < 4; ++c) s[t][c] = (f32x4){0.f, 0.f, 0.f, 0.f};

        #pragma unroll
        for (int kh = 0; kh < 4; ++kh) {
            #pragma unroll
            for (int c = 0; c < 4; ++c) {
                const size_t koff = (size_t)(k0 + c*16 + lr) * 128 + kh*32 + lg*8;
                const bf16x8 kh_ = *(const bf16x8*)(Kh_b + koff);
                const bf16x8 kl_ = *(const bf16x8*)(Kl_b + koff);
                #pragma unroll
                for (int t = 0; t < 2; ++t) {
                    s[t][c] = __builtin_amdgcn_mfma_f32_16x16x32_bf16(qhf[t][kh], kh_, s[t][c], 0, 0, 0);
                    s[t][c] = __builtin_amdgcn_mfma_f32_16x16x32_bf16(qhf[t][kh], kl_, s[t][c], 0, 0, 0);
                    s[t][c] = __builtin_amdgcn_mfma_f32_16x16x32_bf16(qlf[t][kh], kh_, s[t][c], 0, 0, 0);
                }
            }
        }

        const bool domask = (kt >= 2*qt);
        #pragma unroll
        for (int t = 0; t < 2; ++t) {
            #pragma unroll
            for (int c = 0; c < 4; ++c) {
                #pragma unroll
                for (int r = 0; r < 4; ++r) {
                    const int gq = q_base + wv*32 + t*16 + lg*4 + r;
                    const int gk = k0 + c*16 + lr;
                    float v = s[t][c][r];
                    if (domask && gk > gq) v = 0.f;
                    rsum[t][r] += v;
                    const int lrow = wv*32 + t*16 + lg*4 + r;
                    const int byte = lrow*256 + (((c*16 + lr)*4) ^ ((lrow & 7) << 5));
                    *(float*)(s_lds + byte) = v;
                }
            }
        }
        __syncthreads();

        #pragma unroll
        for (int kh2 = 0; kh2 < 2; ++kh2) {
            bf16x8 vh[4], vl[4];
            #pragma unroll
            for (int c = 0; c < 4; ++c) {
                const size_t voff = (size_t)(c*16 + lr) * L_SEQ + k0 + kh2*32 + lg*8;
                vh[c] = *(const bf16x8*)(Vh_b + voff);
                vl[c] = *(const bf16x8*)(Vl_b + voff);
            }
            #pragma unroll
            for (int t = 0; t < 2; ++t) {
                const int lrow = wv*32 + t*16 + lr;
                const int base = lrow*256 + ((kh2*128 + lg*32) ^ ((lrow & 7) << 5));
                float tmp[8];
                *(f32x4*)tmp       = *(const f32x4*)(s_lds + base);
                *(f32x4*)(tmp + 4) = *(const f32x4*)(s_lds + base + 16);
                bf16x8 sh, sl;
                split8(tmp, sh, sl);
                #pragma unroll
                for (int c = 0; c < 4; ++c) {
                    o_acc[t][c] = __builtin_amdgcn_mfma_f32_16x16x32_bf16(sh, vh[c], o_acc[t][c], 0, 0, 0);
                    o_acc[t][c] = __builtin_amdgcn_mfma_f32_16x16x32_bf16(sh, vl[c], o_acc[t][c], 0, 0, 0);
                    o_acc[t][c] = __builtin_amdgcn_mfma_f32_16x16x32_bf16(sl, vh[c], o_acc[t][c], 0, 0, 0);
                }
            }
        }
        __syncthreads();
    }

    // write partial sums (no atomics)
    const size_t slab = (size_t)blockIdx.x * 16 + nh;
    #pragma unroll
    for (int t = 0; t < 2; ++t)
        #pragma unroll
        for (int r = 0; r < 4; ++r) {
            float v = rsum[t][r];
            v += __shfl_xor(v, 1);
            v += __shfl_xor(v, 2);
            v += __shfl_xor(v, 4);
            v += __shfl_xor(v, 8);
            if (lr == 0) {
                const int row = wv*32 + t*16 + lg*4 + r;
                rs_part[slab*128 + row] = v;
            }
        }

    #pragma unroll
    for (int t = 0; t < 2; ++t)
        #pragma unroll
        for (int c = 0; c < 4; ++c)
            #pragma unroll
            for (int r = 0; r < 4; ++r) {
                const int row = wv*32 + t*16 + lg*4 + r;
                O_part[slab*8192 + row*64 + c*16 + lr] = o_acc[t][c][r];
            }
}

// Reduce <=4 chunk partials per (nh,qt), divide by rowsum, write output.
__global__ __launch_bounds__(256) void reduce_div_kernel(
    const float* __restrict__ O_part, const float* __restrict__ rs_part,
    float* __restrict__ out)
{
    const int idx = blockIdx.x * 256 + threadIdx.x;   // 512K threads
    const int d4 = idx & 15;
    const int l  = (idx >> 4) & (L_SEQ - 1);
    const int nh = idx >> 15;
    const int qt = l >> 7;
    const int row = l & 127;
    int cs = 0;
    for (int q = 0; q < qt; ++q) cs += (2*q + 2 + 7) >> 3;
    const int nch = (2*qt + 2 + 7) >> 3;

    float4 o = {0.f, 0.f, 0.f, 0.f};
    float rs = 0.f;
    for (int ci = 0; ci < nch; ++ci) {
        const size_t slab = (size_t)(cs + ci) * 16 + nh;
        const float4 p = *(const float4*)(O_part + slab*8192 + row*64 + d4*4);
        o.x += p.x; o.y += p.y; o.z += p.z; o.w += p.w;
        rs += rs_part[slab*128 + row];
    }
    const float inv = 1.0f / rs;
    float4 r;
    r.x = o.x * inv; r.y = o.y * inv; r.z = o.z * inv; r.w = o.w * inv;
    const int n = nh >> 3, h = nh & 7;
    *(float4*)(out + ((size_t)(n*L_SEQ + l))*DMODEL + h*DHEAD + d4*4) = r;
}

extern "C" void kernel_launch(void* const* d_in, const int* in_sizes, int n_in,
                              void* d_out, int out_size, void* d_ws, size_t ws_size,
                              hipStream_t stream) {
    const float* y         = (const float*)d_in[0];
    const float* positions = (const float*)d_in[1];
    const float* Wq        = (const float*)d_in[2];
    const float* Wk        = (const float*)d_in[3];
    const float* Wv        = (const float*)d_in[4];
    const float* coeff     = (const float*)d_in[5];
    const float* pw        = (const float*)d_in[6];
    const float* pb        = (const float*)d_in[7];
    float* out = (float*)d_out;

    const size_t SQK = (size_t)16 * L_SEQ * 128;    // 4M shorts = 8 MB
    const size_t SV  = (size_t)16 * DHEAD * L_SEQ;  // 2M shorts = 4 MB
    short* Qh = (short*)d_ws;
    short* Ql = Qh + SQK;
    short* Kh = Ql + SQK;
    short* Kl = Kh + SQK;
    short* Vh = Kl + SQK;
    short* Vl = Vh + SV;
    float* O_part  = (float*)(Vl + SV);                         // 40*16*8192 f32 ~ 21 MB
    float* rs_part = O_part + (size_t)NCHUNK * 16 * 128 * 64;   // 40*16*128 f32 = 320 KB

    prep_kernel<<<dim3(32, 8, 3), dim3(256), 0, stream>>>(
        y, positions, Wq, Wk, Wv, coeff, pw, pb, Qh, Ql, Kh, Kl, Vh, Vl);
    attn_kernel<<<dim3(NCHUNK, 16), dim3(256), 0, stream>>>(
        Qh, Ql, Kh, Kl, Vh, Vl, O_part, rs_part);
    reduce_div_kernel<<<dim3(2048), dim3(256), 0, stream>>>(O_part, rs_part, out);
}

// Round 7
// 236.064 us; speedup vs baseline: 1.1494x; 1.1494x over previous
//
#include <hip/hip_runtime.h>
#include <hip/hip_bf16.h>

typedef __attribute__((ext_vector_type(8))) short bf16x8;
typedef __attribute__((ext_vector_type(4))) float f32x4;
typedef unsigned int u32;

#define L_SEQ 2048
#define NHEAD 8
#define DHEAD 64
#define DMODEL 512
#define NCHUNK 51                 // sum over qt of ceil((2qt+2)/6)
#define QK_STRIDE 262144          // per-nh shorts, frag-major Q/K (2048*128)
#define V_STRIDE  131072          // per-nh shorts, frag-major V (2048*64)

__device__ __forceinline__ short f2bf(float f) {
    union { float f; unsigned u; } x; x.f = f;
    unsigned r = x.u + 0x7FFFu + ((x.u >> 16) & 1u);
    return (short)(r >> 16);
}

__device__ __forceinline__ void split1(float x, short& hi, short& lo) {
    unsigned uh = __float_as_uint(x) & 0xFFFF0000u;
    hi = (short)(uh >> 16);
    lo = f2bf(x - __uint_as_float(uh));
}

__device__ __forceinline__ void split8(const float* p, bf16x8& hi, bf16x8& lo) {
    #pragma unroll
    for (int i = 0; i < 8; ++i) {
        float x = p[i];
        unsigned uh = __float_as_uint(x) & 0xFFFF0000u;
        hi[i] = (short)(uh >> 16);
        lo[i] = f2bf(x - __uint_as_float(uh));
    }
}

__device__ __forceinline__ u32 cvtpk_bf16(float a, float b) {
    u32 r;
    asm("v_cvt_pk_bf16_f32 %0, %1, %2" : "=v"(r) : "v"(a), "v"(b));
    return r;
}

// ---------------------------------------------------------------------------
// Kernel 1: C = y @ W^T with split-bf16 3-term MFMA. Epilogues write
// FRAG-MAJOR layouts so attn loads are 16B/lane coalesced:
//   Q/K: idx = nh*QK_STRIDE + ((blk16*4 + kh)*64 + lane)*8 + j
//        lane = (row&15) + 16*((dim>>3)&3), kh = dim>>5, j = dim&7
//        (dim 0..63 = cos*val, 64..127 = sin*val)
//   V:   idx = nh*V_STRIDE + (((key>>5)*4 + (d>>4))*64 + (d&15) + 16*((key>>3)&3))*8 + (key&7)
// Block: 128 rows x 64 cols (one head), 4 waves. Grid (32, 8, 3).
// ---------------------------------------------------------------------------
__global__ __launch_bounds__(256) void prep_kernel(
    const float* __restrict__ y, const float* __restrict__ positions,
    const float* __restrict__ Wq, const float* __restrict__ Wk, const float* __restrict__ Wv,
    const float* __restrict__ coeff, const float* __restrict__ pw, const float* __restrict__ pb,
    short* __restrict__ Qh, short* __restrict__ Ql,
    short* __restrict__ Kh, short* __restrict__ Kl,
    short* __restrict__ Vh, short* __restrict__ Vl)
{
    __shared__ float vtile[128][65];
    const int mode = blockIdx.z;
    const float* W = (mode == 0) ? Wq : (mode == 1) ? Wk : Wv;
    const int m_base = blockIdx.x * 128;
    const int h = blockIdx.y;
    const int n_base = h * 64;
    const int tid = threadIdx.x;
    const int lane = tid & 63;
    const int wv = tid >> 6;
    const int lr = lane & 15;
    const int lg = lane >> 4;

    f32x4 acc[2][4];
    #pragma unroll
    for (int t = 0; t < 2; ++t)
        #pragma unroll
        for (int c = 0; c < 4; ++c) acc[t][c] = (f32x4){0.f, 0.f, 0.f, 0.f};

    for (int kk = 0; kk < DMODEL; kk += 32) {
        bf16x8 ah[2], al[2], bh[4], bl[4];
        #pragma unroll
        for (int t = 0; t < 2; ++t) {
            const float* src = y + (size_t)(m_base + wv*32 + t*16 + lr) * DMODEL + kk + lg*8;
            float tmp[8];
            *(float4*)tmp       = *(const float4*)src;
            *(float4*)(tmp + 4) = *(const float4*)(src + 4);
            split8(tmp, ah[t], al[t]);
        }
        #pragma unroll
        for (int c = 0; c < 4; ++c) {
            const float* src = W + (size_t)(n_base + c*16 + lr) * DMODEL + kk + lg*8;
            float tmp[8];
            *(float4*)tmp       = *(const float4*)src;
            *(float4*)(tmp + 4) = *(const float4*)(src + 4);
            split8(tmp, bh[c], bl[c]);
        }
        #pragma unroll
        for (int t = 0; t < 2; ++t)
            #pragma unroll
            for (int c = 0; c < 4; ++c) {
                acc[t][c] = __builtin_amdgcn_mfma_f32_16x16x32_bf16(ah[t], bh[c], acc[t][c], 0, 0, 0);
                acc[t][c] = __builtin_amdgcn_mfma_f32_16x16x32_bf16(ah[t], bl[c], acc[t][c], 0, 0, 0);
                acc[t][c] = __builtin_amdgcn_mfma_f32_16x16x32_bf16(al[t], bh[c], acc[t][c], 0, 0, 0);
            }
    }

    const int n_idx = m_base >> 11;
    const int nh = n_idx * NHEAD + h;

    if (mode == 2) {
        #pragma unroll
        for (int t = 0; t < 2; ++t)
            #pragma unroll
            for (int c = 0; c < 4; ++c)
                #pragma unroll
                for (int r = 0; r < 4; ++r)
                    vtile[wv*32 + t*16 + lg*4 + r][c*16 + lr] = acc[t][c][r];
        __syncthreads();
        const size_t vbase = (size_t)nh * V_STRIDE;
        #pragma unroll
        for (int i = 0; i < 32; ++i) {
            const int key_l = (tid & 7) + 8*(i & 15);          // 0..127
            const int d     = (tid >> 3) + 32*(i >> 4);        // 0..63
            const int key   = (m_base & (L_SEQ - 1)) + key_l;
            short th, tl;
            split1(vtile[key_l][d], th, tl);
            const size_t idx = vbase +
                ((size_t)((key >> 5)*4 + (d >> 4))*64 + (d & 15) + 16*((key >> 3) & 3))*8 + (key & 7);
            Vh[idx] = th; Vl[idx] = tl;
        }
    } else {
        short* OUTh = (mode == 0) ? Qh : Kh;
        short* OUTl = (mode == 0) ? Ql : Kl;
        const size_t qbase_nh = (size_t)nh * QK_STRIDE;
        #pragma unroll
        for (int t = 0; t < 2; ++t) {
            #pragma unroll
            for (int c = 0; c < 4; ++c) {
                const int d = c*16 + lr;
                const float pwv = pw[n_base + d];
                const float pbv = pb[n_base + d];
                const float cf  = (mode == 0) ? coeff[n_base + d] : 1.0f;
                const int lane_t = 16*((2*c + (lr >> 3)) & 3);  // + (row&15) later
                const int j = lr & 7;
                #pragma unroll
                for (int r = 0; r < 4; ++r) {
                    const int gm = m_base + wv*32 + t*16 + lg*4 + r;
                    const int l = gm & (L_SEQ - 1);
                    const int B = l >> 4;
                    const float posv = positions[gm];
                    const float x = acc[t][c][r];
                    const float sp = fmaxf(x, 0.f) + __logf(1.f + __expf(-fabsf(x)));
                    const float p = pwv * posv + pbv;
                    const float cs = __cosf(p), sn = __sinf(p);
                    short h1, l1, h2, l2;
                    split1(sp * cf * cs, h1, l1);
                    split1(sp * cf * sn, h2, l2);
                    const int ln = (l & 15) + lane_t;
                    const size_t idx_c = qbase_nh + ((size_t)(B*4 + (c >> 1))*64 + ln)*8 + j;
                    const size_t idx_s = qbase_nh + ((size_t)(B*4 + 2 + (c >> 1))*64 + ln)*8 + j;
                    OUTh[idx_c] = h1; OUTl[idx_c] = l1;
                    OUTh[idx_s] = h2; OUTl[idx_s] = l2;
                }
            }
        }
    }
}

// ---------------------------------------------------------------------------
// Kernel 2: split-K causal attention, NO LDS / NO BARRIERS.
// Swapped QK (mfma(K,Q) -> S^T): lane (lr,lg) holds S[q=lr][key=c*16+lg*4+r].
// PV A-frags assembled in-register via ds_bpermute (key regroup across lane
// groups) + trunc/cvt_pk split. All global loads 16B/lane coalesced
// (frag-major layouts). Each block: 128 q rows x up to 6 k-steps of 64 keys;
// partials to slabs. Grid (51, 16), 4 independent waves.
// ---------------------------------------------------------------------------
__global__ __launch_bounds__(256) void attn_kernel(
    const short* __restrict__ Qh, const short* __restrict__ Ql,
    const short* __restrict__ Kh, const short* __restrict__ Kl,
    const short* __restrict__ Vh, const short* __restrict__ Vl,
    float* __restrict__ O_part, float* __restrict__ rs_part)
{
    // map blockIdx.x (chunk slot) -> (qt, chunk index)
    int rem = blockIdx.x, qt = 0;
    for (qt = 0; qt < 16; ++qt) {
        const int nch = (2*qt + 2 + 5) / 6;
        if (rem < nch) break;
        rem -= nch;
    }
    const int nst = 2*qt + 2;
    const int kt0 = rem * 6;
    const int kt1 = (kt0 + 6 < nst) ? (kt0 + 6) : nst;

    const int nh = blockIdx.y;
    const int q_base = qt * 128;
    const int tid = threadIdx.x;
    const int lane = tid & 63;
    const int wv = tid >> 6;
    const int lr = lane & 15;
    const int lg = lane >> 4;

    const short* Qh_b = Qh + (size_t)nh * QK_STRIDE;
    const short* Ql_b = Ql + (size_t)nh * QK_STRIDE;
    const short* Kh_b = Kh + (size_t)nh * QK_STRIDE;
    const short* Kl_b = Kl + (size_t)nh * QK_STRIDE;
    const short* Vh_b = Vh + (size_t)nh * V_STRIDE;
    const short* Vl_b = Vl + (size_t)nh * V_STRIDE;

    // Q fragments (B-operand), hoisted. Bq = qt*8 + wv*2 + t
    bf16x8 qh[2][4], ql[2][4];
    #pragma unroll
    for (int t = 0; t < 2; ++t) {
        const int Bq = qt*8 + wv*2 + t;
        #pragma unroll
        for (int kh = 0; kh < 4; ++kh) {
            const size_t off = ((size_t)(Bq*4 + kh)*64 + lane)*8;
            qh[t][kh] = *(const bf16x8*)(Qh_b + off);
            ql[t][kh] = *(const bf16x8*)(Ql_b + off);
        }
    }

    f32x4 o_acc[2][4];
    float rs[2];
    #pragma unroll
    for (int t = 0; t < 2; ++t) {
        #pragma unroll
        for (int c = 0; c < 4; ++c) o_acc[t][c] = (f32x4){0.f, 0.f, 0.f, 0.f};
        rs[t] = 0.f;
    }

    const int addr0 = (lr + ((lg & 1) * 2) * 16) << 2;
    const int addr1 = addr0 + 64;
    const bool selhi = (lg >= 2);

    for (int kt = kt0; kt < kt1; ++kt) {
        const int k0 = kt * 64;

        // ---- QK^T (swapped): st[t][c] = S^T fragments ----
        f32x4 st[2][4];
        #pragma unroll
        for (int t = 0; t < 2; ++t)
            #pragma unroll
            for (int c = 0; c < 4; ++c) st[t][c] = (f32x4){0.f, 0.f, 0.f, 0.f};

        #pragma unroll
        for (int kh = 0; kh < 4; ++kh) {
            #pragma unroll
            for (int c = 0; c < 4; ++c) {
                const int Bk = (k0 >> 4) + c;
                const size_t off = ((size_t)(Bk*4 + kh)*64 + lane)*8;
                const bf16x8 kfh = *(const bf16x8*)(Kh_b + off);
                const bf16x8 kfl = *(const bf16x8*)(Kl_b + off);
                #pragma unroll
                for (int t = 0; t < 2; ++t) {
                    st[t][c] = __builtin_amdgcn_mfma_f32_16x16x32_bf16(kfh, qh[t][kh], st[t][c], 0, 0, 0);
                    st[t][c] = __builtin_amdgcn_mfma_f32_16x16x32_bf16(kfh, ql[t][kh], st[t][c], 0, 0, 0);
                    st[t][c] = __builtin_amdgcn_mfma_f32_16x16x32_bf16(kfl, qh[t][kh], st[t][c], 0, 0, 0);
                }
            }
        }

        // ---- mask + rowsum (in-register) ----
        const bool domask = (kt >= 2*qt);
        #pragma unroll
        for (int t = 0; t < 2; ++t) {
            const int gq = q_base + wv*32 + t*16 + lr;
            float part = 0.f;
            #pragma unroll
            for (int c = 0; c < 4; ++c)
                #pragma unroll
                for (int r = 0; r < 4; ++r) {
                    const int gk = k0 + c*16 + lg*4 + r;
                    float v = st[t][c][r];
                    if (domask && gk > gq) v = 0.f;
                    st[t][c][r] = v;
                    part += v;
                }
            part += __shfl_xor(part, 16);
            part += __shfl_xor(part, 32);
            rs[t] += part;
        }

        // ---- pack S^T to bf16 hi/lo words ----
        u32 pwh[2][4][2], pwl[2][4][2];
        #pragma unroll
        for (int t = 0; t < 2; ++t)
            #pragma unroll
            for (int c = 0; c < 4; ++c) {
                const u32 b0 = __float_as_uint(st[t][c][0]);
                const u32 b1 = __float_as_uint(st[t][c][1]);
                const u32 b2 = __float_as_uint(st[t][c][2]);
                const u32 b3 = __float_as_uint(st[t][c][3]);
                pwh[t][c][0] = (b1 & 0xFFFF0000u) | (b0 >> 16);
                pwh[t][c][1] = (b3 & 0xFFFF0000u) | (b2 >> 16);
                const float l0 = st[t][c][0] - __uint_as_float(b0 & 0xFFFF0000u);
                const float l1 = st[t][c][1] - __uint_as_float(b1 & 0xFFFF0000u);
                const float l2 = st[t][c][2] - __uint_as_float(b2 & 0xFFFF0000u);
                const float l3 = st[t][c][3] - __uint_as_float(b3 & 0xFFFF0000u);
                pwl[t][c][0] = cvtpk_bf16(l0, l1);
                pwl[t][c][1] = cvtpk_bf16(l2, l3);
            }

        // ---- PV: gather PA frags via bpermute, mfma with V frags ----
        #pragma unroll
        for (int kc = 0; kc < 2; ++kc) {
            union { u32 u[4]; bf16x8 v; } pah[2], pal[2];
            #pragma unroll
            for (int t = 0; t < 2; ++t) {
                u32 a, b;
                a = (u32)__builtin_amdgcn_ds_bpermute(addr0, (int)pwh[t][2*kc][0]);
                b = (u32)__builtin_amdgcn_ds_bpermute(addr0, (int)pwh[t][2*kc+1][0]);
                pah[t].u[0] = selhi ? b : a;
                a = (u32)__builtin_amdgcn_ds_bpermute(addr0, (int)pwh[t][2*kc][1]);
                b = (u32)__builtin_amdgcn_ds_bpermute(addr0, (int)pwh[t][2*kc+1][1]);
                pah[t].u[1] = selhi ? b : a;
                a = (u32)__builtin_amdgcn_ds_bpermute(addr1, (int)pwh[t][2*kc][0]);
                b = (u32)__builtin_amdgcn_ds_bpermute(addr1, (int)pwh[t][2*kc+1][0]);
                pah[t].u[2] = selhi ? b : a;
                a = (u32)__builtin_amdgcn_ds_bpermute(addr1, (int)pwh[t][2*kc][1]);
                b = (u32)__builtin_amdgcn_ds_bpermute(addr1, (int)pwh[t][2*kc+1][1]);
                pah[t].u[3] = selhi ? b : a;

                a = (u32)__builtin_amdgcn_ds_bpermute(addr0, (int)pwl[t][2*kc][0]);
                b = (u32)__builtin_amdgcn_ds_bpermute(addr0, (int)pwl[t][2*kc+1][0]);
                pal[t].u[0] = selhi ? b : a;
                a = (u32)__builtin_amdgcn_ds_bpermute(addr0, (int)pwl[t][2*kc][1]);
                b = (u32)__builtin_amdgcn_ds_bpermute(addr0, (int)pwl[t][2*kc+1][1]);
                pal[t].u[1] = selhi ? b : a;
                a = (u32)__builtin_amdgcn_ds_bpermute(addr1, (int)pwl[t][2*kc][0]);
                b = (u32)__builtin_amdgcn_ds_bpermute(addr1, (int)pwl[t][2*kc+1][0]);
                pal[t].u[2] = selhi ? b : a;
                a = (u32)__builtin_amdgcn_ds_bpermute(addr1, (int)pwl[t][2*kc][1]);
                b = (u32)__builtin_amdgcn_ds_bpermute(addr1, (int)pwl[t][2*kc+1][1]);
                pal[t].u[3] = selhi ? b : a;
            }
            const int Bk32 = (k0 >> 5) + kc;
            #pragma unroll
            for (int cd = 0; cd < 4; ++cd) {
                const size_t voff = ((size_t)(Bk32*4 + cd)*64 + lane)*8;
                const bf16x8 vfh = *(const bf16x8*)(Vh_b + voff);
                const bf16x8 vfl = *(const bf16x8*)(Vl_b + voff);
                #pragma unroll
                for (int t = 0; t < 2; ++t) {
                    o_acc[t][cd] = __builtin_amdgcn_mfma_f32_16x16x32_bf16(pah[t].v, vfh, o_acc[t][cd], 0, 0, 0);
                    o_acc[t][cd] = __builtin_amdgcn_mfma_f32_16x16x32_bf16(pah[t].v, vfl, o_acc[t][cd], 0, 0, 0);
                    o_acc[t][cd] = __builtin_amdgcn_mfma_f32_16x16x32_bf16(pal[t].v, vfh, o_acc[t][cd], 0, 0, 0);
                }
            }
        }
    }

    // ---- write partials (no atomics) ----
    const size_t slab = (size_t)blockIdx.x * 16 + nh;
    #pragma unroll
    for (int t = 0; t < 2; ++t)
        if (lg == 0)
            rs_part[slab*128 + wv*32 + t*16 + lr] = rs[t];

    #pragma unroll
    for (int t = 0; t < 2; ++t)
        #pragma unroll
        for (int cd = 0; cd < 4; ++cd)
            #pragma unroll
            for (int r = 0; r < 4; ++r) {
                const int row = wv*32 + t*16 + lg*4 + r;
                O_part[slab*8192 + row*64 + cd*16 + lr] = o_acc[t][cd][r];
            }
}

// Reduce chunk partials per (nh,qt), divide by rowsum, write output.
__global__ __launch_bounds__(256) void reduce_div_kernel(
    const float* __restrict__ O_part, const float* __restrict__ rs_part,
    float* __restrict__ out)
{
    const int idx = blockIdx.x * 256 + threadIdx.x;   // 512K threads
    const int d4 = idx & 15;
    const int l  = (idx >> 4) & (L_SEQ - 1);
    const int nh = idx >> 15;
    const int qt = l >> 7;
    const int row = l & 127;
    int cs = 0;
    for (int q = 0; q < qt; ++q) cs += (2*q + 2 + 5) / 6;
    const int nch = (2*qt + 2 + 5) / 6;

    float4 o = {0.f, 0.f, 0.f, 0.f};
    float rssum = 0.f;
    for (int ci = 0; ci < nch; ++ci) {
        const size_t slab = (size_t)(cs + ci) * 16 + nh;
        const float4 p = *(const float4*)(O_part + slab*8192 + row*64 + d4*4);
        o.x += p.x; o.y += p.y; o.z += p.z; o.w += p.w;
        rssum += rs_part[slab*128 + row];
    }
    const float inv = 1.0f / rssum;
    float4 r;
    r.x = o.x * inv; r.y = o.y * inv; r.z = o.z * inv; r.w = o.w * inv;
    const int n = nh >> 3, h = nh & 7;
    *(float4*)(out + ((size_t)(n*L_SEQ + l))*DMODEL + h*DHEAD + d4*4) = r;
}

extern "C" void kernel_launch(void* const* d_in, const int* in_sizes, int n_in,
                              void* d_out, int out_size, void* d_ws, size_t ws_size,
                              hipStream_t stream) {
    const float* y         = (const float*)d_in[0];
    const float* positions = (const float*)d_in[1];
    const float* Wq        = (const float*)d_in[2];
    const float* Wk        = (const float*)d_in[3];
    const float* Wv        = (const float*)d_in[4];
    const float* coeff     = (const float*)d_in[5];
    const float* pw        = (const float*)d_in[6];
    const float* pb        = (const float*)d_in[7];
    float* out = (float*)d_out;

    const size_t SQK = (size_t)16 * QK_STRIDE;   // 4M shorts = 8 MB each
    const size_t SV  = (size_t)16 * V_STRIDE;    // 2M shorts = 4 MB each
    short* Qh = (short*)d_ws;
    short* Ql = Qh + SQK;
    short* Kh = Ql + SQK;
    short* Kl = Kh + SQK;
    short* Vh = Kl + SQK;
    short* Vl = Vh + SV;
    float* O_part  = (float*)(Vl + SV);                         // 51*16*8192 f32 ~ 25.5 MB
    float* rs_part = O_part + (size_t)NCHUNK * 16 * 128 * 64;   // 51*16*128 f32 ~ 0.4 MB

    prep_kernel<<<dim3(32, 8, 3), dim3(256), 0, stream>>>(
        y, positions, Wq, Wk, Wv, coeff, pw, pb, Qh, Ql, Kh, Kl, Vh, Vl);
    attn_kernel<<<dim3(NCHUNK, 16), dim3(256), 0, stream>>>(
        Qh, Ql, Kh, Kl, Vh, Vl, O_part, rs_part);
    reduce_div_kernel<<<dim3(2048), dim3(256), 0, stream>>>(O_part, rs_part, out);
}

// Round 8
// 215.002 us; speedup vs baseline: 1.2620x; 1.0980x over previous
//
#include <hip/hip_runtime.h>
#include <hip/hip_bf16.h>

typedef __attribute__((ext_vector_type(8))) short bf16x8;
typedef __attribute__((ext_vector_type(4))) float f32x4;
typedef unsigned int u32;

#define L_SEQ 2048
#define NHEAD 8
#define DHEAD 64
#define DMODEL 512
#define QK_STRIDE 262144          // per-nh shorts, frag-major Q/K (2048*128)
#define V_STRIDE  131072          // per-nh shorts, frag-major V (2048*64)

__device__ __forceinline__ short f2bf(float f) {
    union { float f; unsigned u; } x; x.f = f;
    unsigned r = x.u + 0x7FFFu + ((x.u >> 16) & 1u);
    return (short)(r >> 16);
}

__device__ __forceinline__ void split1(float x, short& hi, short& lo) {
    unsigned uh = __float_as_uint(x) & 0xFFFF0000u;
    hi = (short)(uh >> 16);
    lo = f2bf(x - __uint_as_float(uh));
}

__device__ __forceinline__ void split8(const float* p, bf16x8& hi, bf16x8& lo) {
    #pragma unroll
    for (int i = 0; i < 8; ++i) {
        float x = p[i];
        unsigned uh = __float_as_uint(x) & 0xFFFF0000u;
        hi[i] = (short)(uh >> 16);
        lo[i] = f2bf(x - __uint_as_float(uh));
    }
}

__device__ __forceinline__ u32 cvtpk_bf16(float a, float b) {
    u32 r;
    asm("v_cvt_pk_bf16_f32 %0, %1, %2" : "=v"(r) : "v"(a), "v"(b));
    return r;
}

// ---------------------------------------------------------------------------
// Kernel 1: C = y @ W^T with split-bf16 3-term MFMA. Epilogues write
// FRAG-MAJOR layouts so attn loads are 16B/lane coalesced (see R7).
// ---------------------------------------------------------------------------
__global__ __launch_bounds__(256) void prep_kernel(
    const float* __restrict__ y, const float* __restrict__ positions,
    const float* __restrict__ Wq, const float* __restrict__ Wk, const float* __restrict__ Wv,
    const float* __restrict__ coeff, const float* __restrict__ pw, const float* __restrict__ pb,
    short* __restrict__ Qh, short* __restrict__ Ql,
    short* __restrict__ Kh, short* __restrict__ Kl,
    short* __restrict__ Vh, short* __restrict__ Vl)
{
    __shared__ float vtile[128][65];
    const int mode = blockIdx.z;
    const float* W = (mode == 0) ? Wq : (mode == 1) ? Wk : Wv;
    const int m_base = blockIdx.x * 128;
    const int h = blockIdx.y;
    const int n_base = h * 64;
    const int tid = threadIdx.x;
    const int lane = tid & 63;
    const int wv = tid >> 6;
    const int lr = lane & 15;
    const int lg = lane >> 4;

    f32x4 acc[2][4];
    #pragma unroll
    for (int t = 0; t < 2; ++t)
        #pragma unroll
        for (int c = 0; c < 4; ++c) acc[t][c] = (f32x4){0.f, 0.f, 0.f, 0.f};

    for (int kk = 0; kk < DMODEL; kk += 32) {
        bf16x8 ah[2], al[2], bh[4], bl[4];
        #pragma unroll
        for (int t = 0; t < 2; ++t) {
            const float* src = y + (size_t)(m_base + wv*32 + t*16 + lr) * DMODEL + kk + lg*8;
            float tmp[8];
            *(float4*)tmp       = *(const float4*)src;
            *(float4*)(tmp + 4) = *(const float4*)(src + 4);
            split8(tmp, ah[t], al[t]);
        }
        #pragma unroll
        for (int c = 0; c < 4; ++c) {
            const float* src = W + (size_t)(n_base + c*16 + lr) * DMODEL + kk + lg*8;
            float tmp[8];
            *(float4*)tmp       = *(const float4*)src;
            *(float4*)(tmp + 4) = *(const float4*)(src + 4);
            split8(tmp, bh[c], bl[c]);
        }
        #pragma unroll
        for (int t = 0; t < 2; ++t)
            #pragma unroll
            for (int c = 0; c < 4; ++c) {
                acc[t][c] = __builtin_amdgcn_mfma_f32_16x16x32_bf16(ah[t], bh[c], acc[t][c], 0, 0, 0);
                acc[t][c] = __builtin_amdgcn_mfma_f32_16x16x32_bf16(ah[t], bl[c], acc[t][c], 0, 0, 0);
                acc[t][c] = __builtin_amdgcn_mfma_f32_16x16x32_bf16(al[t], bh[c], acc[t][c], 0, 0, 0);
            }
    }

    const int n_idx = m_base >> 11;
    const int nh = n_idx * NHEAD + h;

    if (mode == 2) {
        #pragma unroll
        for (int t = 0; t < 2; ++t)
            #pragma unroll
            for (int c = 0; c < 4; ++c)
                #pragma unroll
                for (int r = 0; r < 4; ++r)
                    vtile[wv*32 + t*16 + lg*4 + r][c*16 + lr] = acc[t][c][r];
        __syncthreads();
        const size_t vbase = (size_t)nh * V_STRIDE;
        #pragma unroll
        for (int i = 0; i < 32; ++i) {
            const int key_l = (tid & 7) + 8*(i & 15);          // 0..127
            const int d     = (tid >> 3) + 32*(i >> 4);        // 0..63
            const int key   = (m_base & (L_SEQ - 1)) + key_l;
            short th, tl;
            split1(vtile[key_l][d], th, tl);
            const size_t idx = vbase +
                ((size_t)((key >> 5)*4 + (d >> 4))*64 + (d & 15) + 16*((key >> 3) & 3))*8 + (key & 7);
            Vh[idx] = th; Vl[idx] = tl;
        }
    } else {
        short* OUTh = (mode == 0) ? Qh : Kh;
        short* OUTl = (mode == 0) ? Ql : Kl;
        const size_t qbase_nh = (size_t)nh * QK_STRIDE;
        #pragma unroll
        for (int t = 0; t < 2; ++t) {
            #pragma unroll
            for (int c = 0; c < 4; ++c) {
                const int d = c*16 + lr;
                const float pwv = pw[n_base + d];
                const float pbv = pb[n_base + d];
                const float cf  = (mode == 0) ? coeff[n_base + d] : 1.0f;
                const int lane_t = 16*((2*c + (lr >> 3)) & 3);
                const int j = lr & 7;
                #pragma unroll
                for (int r = 0; r < 4; ++r) {
                    const int gm = m_base + wv*32 + t*16 + lg*4 + r;
                    const int l = gm & (L_SEQ - 1);
                    const int B = l >> 4;
                    const float posv = positions[gm];
                    const float x = acc[t][c][r];
                    const float sp = fmaxf(x, 0.f) + __logf(1.f + __expf(-fabsf(x)));
                    const float p = pwv * posv + pbv;
                    const float cs = __cosf(p), sn = __sinf(p);
                    short h1, l1, h2, l2;
                    split1(sp * cf * cs, h1, l1);
                    split1(sp * cf * sn, h2, l2);
                    const int ln = (l & 15) + lane_t;
                    const size_t idx_c = qbase_nh + ((size_t)(B*4 + (c >> 1))*64 + ln)*8 + j;
                    const size_t idx_s = qbase_nh + ((size_t)(B*4 + 2 + (c >> 1))*64 + ln)*8 + j;
                    OUTh[idx_c] = h1; OUTl[idx_c] = l1;
                    OUTh[idx_s] = h2; OUTl[idx_s] = l2;
                }
            }
        }
    }
}

// ---------------------------------------------------------------------------
// Kernel 2: split-K causal attention, no LDS tile / no barriers (R7 struct).
// R8: uniform CHUNK-kstep blocks (CHUNK=2 -> perfectly balanced grid),
// rolling K c+1 register prefetch, early V-hi issue. Swapped QK (S^T frags),
// PV A-frags via ds_bpermute. Partials to per-slot slabs.
// ---------------------------------------------------------------------------
template<int CHUNK>
__global__ __launch_bounds__(256) void attn_kernel(
    const short* __restrict__ Qh, const short* __restrict__ Ql,
    const short* __restrict__ Kh, const short* __restrict__ Kl,
    const short* __restrict__ Vh, const short* __restrict__ Vl,
    float* __restrict__ O_part, float* __restrict__ rs_part)
{
    // map blockIdx.x (chunk slot) -> (qt, chunk index)
    int rem = blockIdx.x, qt = 0;
    for (qt = 0; qt < 16; ++qt) {
        const int nch = (2*qt + 2 + CHUNK - 1) / CHUNK;
        if (rem < nch) break;
        rem -= nch;
    }
    const int nst = 2*qt + 2;
    const int kt0 = rem * CHUNK;
    const int kt1 = (kt0 + CHUNK < nst) ? (kt0 + CHUNK) : nst;

    const int nh = blockIdx.y;
    const int q_base = qt * 128;
    const int tid = threadIdx.x;
    const int lane = tid & 63;
    const int wv = tid >> 6;
    const int lr = lane & 15;
    const int lg = lane >> 4;

    const short* Qh_b = Qh + (size_t)nh * QK_STRIDE;
    const short* Ql_b = Ql + (size_t)nh * QK_STRIDE;
    const short* Kh_b = Kh + (size_t)nh * QK_STRIDE;
    const short* Kl_b = Kl + (size_t)nh * QK_STRIDE;
    const short* Vh_b = Vh + (size_t)nh * V_STRIDE;
    const short* Vl_b = Vl + (size_t)nh * V_STRIDE;

    // Q fragments (B-operand), hoisted. Bq = qt*8 + wv*2 + t
    bf16x8 qh[2][4], ql[2][4];
    #pragma unroll
    for (int t = 0; t < 2; ++t) {
        const int Bq = qt*8 + wv*2 + t;
        #pragma unroll
        for (int kh = 0; kh < 4; ++kh) {
            const size_t off = ((size_t)(Bq*4 + kh)*64 + lane)*8;
            qh[t][kh] = *(const bf16x8*)(Qh_b + off);
            ql[t][kh] = *(const bf16x8*)(Ql_b + off);
        }
    }

    f32x4 o_acc[2][4];
    float rs[2];
    #pragma unroll
    for (int t = 0; t < 2; ++t) {
        #pragma unroll
        for (int c = 0; c < 4; ++c) o_acc[t][c] = (f32x4){0.f, 0.f, 0.f, 0.f};
        rs[t] = 0.f;
    }

    const int addr0 = (lr + ((lg & 1) * 2) * 16) << 2;
    const int addr1 = addr0 + 64;
    const bool selhi = (lg >= 2);

    for (int kt = kt0; kt < kt1; ++kt) {
        const int k0 = kt * 64;
        const int Bk0 = k0 >> 4;

        // ---- QK^T (swapped) with rolling c+1 K prefetch ----
        f32x4 st[2][4];
        #pragma unroll
        for (int t = 0; t < 2; ++t)
            #pragma unroll
            for (int c = 0; c < 4; ++c) st[t][c] = (f32x4){0.f, 0.f, 0.f, 0.f};

        bf16x8 kfh[2][4], kfl[2][4];     // double-buffer over c
        #pragma unroll
        for (int kh = 0; kh < 4; ++kh) {
            const size_t off = ((size_t)(Bk0*4 + kh)*64 + lane)*8;
            kfh[0][kh] = *(const bf16x8*)(Kh_b + off);
            kfl[0][kh] = *(const bf16x8*)(Kl_b + off);
        }
        #pragma unroll
        for (int c = 0; c < 4; ++c) {
            const int cb = c & 1, nb = cb ^ 1;
            if (c < 3) {
                #pragma unroll
                for (int kh = 0; kh < 4; ++kh) {
                    const size_t off = ((size_t)((Bk0 + c + 1)*4 + kh)*64 + lane)*8;
                    kfh[nb][kh] = *(const bf16x8*)(Kh_b + off);
                    kfl[nb][kh] = *(const bf16x8*)(Kl_b + off);
                }
            }
            #pragma unroll
            for (int kh = 0; kh < 4; ++kh)
                #pragma unroll
                for (int t = 0; t < 2; ++t) {
                    st[t][c] = __builtin_amdgcn_mfma_f32_16x16x32_bf16(kfh[cb][kh], qh[t][kh], st[t][c], 0, 0, 0);
                    st[t][c] = __builtin_amdgcn_mfma_f32_16x16x32_bf16(kfh[cb][kh], ql[t][kh], st[t][c], 0, 0, 0);
                    st[t][c] = __builtin_amdgcn_mfma_f32_16x16x32_bf16(kfl[cb][kh], qh[t][kh], st[t][c], 0, 0, 0);
                }
        }

        // ---- early V-hi issue (lands during pack + bpermute) ----
        bf16x8 vfh[2][4];
        #pragma unroll
        for (int kc = 0; kc < 2; ++kc)
            #pragma unroll
            for (int cd = 0; cd < 4; ++cd) {
                const size_t voff = ((size_t)(((k0 >> 5) + kc)*4 + cd)*64 + lane)*8;
                vfh[kc][cd] = *(const bf16x8*)(Vh_b + voff);
            }

        // ---- mask + rowsum (in-register) ----
        const bool domask = (kt >= 2*qt);
        #pragma unroll
        for (int t = 0; t < 2; ++t) {
            const int gq = q_base + wv*32 + t*16 + lr;
            float part = 0.f;
            #pragma unroll
            for (int c = 0; c < 4; ++c)
                #pragma unroll
                for (int r = 0; r < 4; ++r) {
                    const int gk = k0 + c*16 + lg*4 + r;
                    float v = st[t][c][r];
                    if (domask && gk > gq) v = 0.f;
                    st[t][c][r] = v;
                    part += v;
                }
            part += __shfl_xor(part, 16);
            part += __shfl_xor(part, 32);
            rs[t] += part;
        }

        // ---- pack S^T to bf16 hi/lo words ----
        u32 pwh[2][4][2], pwl[2][4][2];
        #pragma unroll
        for (int t = 0; t < 2; ++t)
            #pragma unroll
            for (int c = 0; c < 4; ++c) {
                const u32 b0 = __float_as_uint(st[t][c][0]);
                const u32 b1 = __float_as_uint(st[t][c][1]);
                const u32 b2 = __float_as_uint(st[t][c][2]);
                const u32 b3 = __float_as_uint(st[t][c][3]);
                pwh[t][c][0] = (b1 & 0xFFFF0000u) | (b0 >> 16);
                pwh[t][c][1] = (b3 & 0xFFFF0000u) | (b2 >> 16);
                const float l0 = st[t][c][0] - __uint_as_float(b0 & 0xFFFF0000u);
                const float l1 = st[t][c][1] - __uint_as_float(b1 & 0xFFFF0000u);
                const float l2 = st[t][c][2] - __uint_as_float(b2 & 0xFFFF0000u);
                const float l3 = st[t][c][3] - __uint_as_float(b3 & 0xFFFF0000u);
                pwl[t][c][0] = cvtpk_bf16(l0, l1);
                pwl[t][c][1] = cvtpk_bf16(l2, l3);
            }

        // ---- PV: gather PA frags via bpermute, mfma with V frags ----
        #pragma unroll
        for (int kc = 0; kc < 2; ++kc) {
            // V-lo for this kc (V-hi already in flight/registers)
            bf16x8 vfl[4];
            #pragma unroll
            for (int cd = 0; cd < 4; ++cd) {
                const size_t voff = ((size_t)(((k0 >> 5) + kc)*4 + cd)*64 + lane)*8;
                vfl[cd] = *(const bf16x8*)(Vl_b + voff);
            }
            union { u32 u[4]; bf16x8 v; } pah[2], pal[2];
            #pragma unroll
            for (int t = 0; t < 2; ++t) {
                u32 a, b;
                a = (u32)__builtin_amdgcn_ds_bpermute(addr0, (int)pwh[t][2*kc][0]);
                b = (u32)__builtin_amdgcn_ds_bpermute(addr0, (int)pwh[t][2*kc+1][0]);
                pah[t].u[0] = selhi ? b : a;
                a = (u32)__builtin_amdgcn_ds_bpermute(addr0, (int)pwh[t][2*kc][1]);
                b = (u32)__builtin_amdgcn_ds_bpermute(addr0, (int)pwh[t][2*kc+1][1]);
                pah[t].u[1] = selhi ? b : a;
                a = (u32)__builtin_amdgcn_ds_bpermute(addr1, (int)pwh[t][2*kc][0]);
                b = (u32)__builtin_amdgcn_ds_bpermute(addr1, (int)pwh[t][2*kc+1][0]);
                pah[t].u[2] = selhi ? b : a;
                a = (u32)__builtin_amdgcn_ds_bpermute(addr1, (int)pwh[t][2*kc][1]);
                b = (u32)__builtin_amdgcn_ds_bpermute(addr1, (int)pwh[t][2*kc+1][1]);
                pah[t].u[3] = selhi ? b : a;

                a = (u32)__builtin_amdgcn_ds_bpermute(addr0, (int)pwl[t][2*kc][0]);
                b = (u32)__builtin_amdgcn_ds_bpermute(addr0, (int)pwl[t][2*kc+1][0]);
                pal[t].u[0] = selhi ? b : a;
                a = (u32)__builtin_amdgcn_ds_bpermute(addr0, (int)pwl[t][2*kc][1]);
                b = (u32)__builtin_amdgcn_ds_bpermute(addr0, (int)pwl[t][2*kc+1][1]);
                pal[t].u[1] = selhi ? b : a;
                a = (u32)__builtin_amdgcn_ds_bpermute(addr1, (int)pwl[t][2*kc][0]);
                b = (u32)__builtin_amdgcn_ds_bpermute(addr1, (int)pwl[t][2*kc+1][0]);
                pal[t].u[2] = selhi ? b : a;
                a = (u32)__builtin_amdgcn_ds_bpermute(addr1, (int)pwl[t][2*kc][1]);
                b = (u32)__builtin_amdgcn_ds_bpermute(addr1, (int)pwl[t][2*kc+1][1]);
                pal[t].u[3] = selhi ? b : a;
            }
            #pragma unroll
            for (int cd = 0; cd < 4; ++cd) {
                #pragma unroll
                for (int t = 0; t < 2; ++t) {
                    o_acc[t][cd] = __builtin_amdgcn_mfma_f32_16x16x32_bf16(pah[t].v, vfh[kc][cd], o_acc[t][cd], 0, 0, 0);
                    o_acc[t][cd] = __builtin_amdgcn_mfma_f32_16x16x32_bf16(pah[t].v, vfl[cd],     o_acc[t][cd], 0, 0, 0);
                    o_acc[t][cd] = __builtin_amdgcn_mfma_f32_16x16x32_bf16(pal[t].v, vfh[kc][cd], o_acc[t][cd], 0, 0, 0);
                }
            }
        }
    }

    // ---- write partials (no atomics) ----
    const size_t slab = (size_t)blockIdx.x * 16 + nh;
    #pragma unroll
    for (int t = 0; t < 2; ++t)
        if (lg == 0)
            rs_part[slab*128 + wv*32 + t*16 + lr] = rs[t];

    #pragma unroll
    for (int t = 0; t < 2; ++t)
        #pragma unroll
        for (int cd = 0; cd < 4; ++cd)
            #pragma unroll
            for (int r = 0; r < 4; ++r) {
                const int row = wv*32 + t*16 + lg*4 + r;
                O_part[slab*8192 + row*64 + cd*16 + lr] = o_acc[t][cd][r];
            }
}

// Reduce chunk partials per (nh,qt), divide by rowsum, write output.
template<int CHUNK>
__global__ __launch_bounds__(256) void reduce_div_kernel(
    const float* __restrict__ O_part, const float* __restrict__ rs_part,
    float* __restrict__ out)
{
    const int idx = blockIdx.x * 256 + threadIdx.x;   // 512K threads
    const int d4 = idx & 15;
    const int l  = (idx >> 4) & (L_SEQ - 1);
    const int nh = idx >> 15;
    const int qt = l >> 7;
    const int row = l & 127;
    int cs = 0;
    for (int q = 0; q < qt; ++q) cs += (2*q + 2 + CHUNK - 1) / CHUNK;
    const int nch = (2*qt + 2 + CHUNK - 1) / CHUNK;

    float4 o = {0.f, 0.f, 0.f, 0.f};
    float rssum = 0.f;
    for (int ci = 0; ci < nch; ++ci) {
        const size_t slab = (size_t)(cs + ci) * 16 + nh;
        const float4 p = *(const float4*)(O_part + slab*8192 + row*64 + d4*4);
        o.x += p.x; o.y += p.y; o.z += p.z; o.w += p.w;
        rssum += rs_part[slab*128 + row];
    }
    const float inv = 1.0f / rssum;
    float4 r;
    r.x = o.x * inv; r.y = o.y * inv; r.z = o.z * inv; r.w = o.w * inv;
    const int n = nh >> 3, h = nh & 7;
    *(float4*)(out + ((size_t)(n*L_SEQ + l))*DMODEL + h*DHEAD + d4*4) = r;
}

extern "C" void kernel_launch(void* const* d_in, const int* in_sizes, int n_in,
                              void* d_out, int out_size, void* d_ws, size_t ws_size,
                              hipStream_t stream) {
    const float* y         = (const float*)d_in[0];
    const float* positions = (const float*)d_in[1];
    const float* Wq        = (const float*)d_in[2];
    const float* Wk        = (const float*)d_in[3];
    const float* Wv        = (const float*)d_in[4];
    const float* coeff     = (const float*)d_in[5];
    const float* pw        = (const float*)d_in[6];
    const float* pb        = (const float*)d_in[7];
    float* out = (float*)d_out;

    const size_t SQK = (size_t)16 * QK_STRIDE;   // shorts
    const size_t SV  = (size_t)16 * V_STRIDE;
    short* Qh = (short*)d_ws;
    short* Ql = Qh + SQK;
    short* Kh = Ql + SQK;
    short* Kl = Kh + SQK;
    short* Vh = Kl + SQK;
    short* Vl = Vh + SV;
    float* O_part = (float*)(Vl + SV);
    const size_t base_bytes = (SQK*4 + SV*2) * sizeof(short);
    const size_t per_slot   = (size_t)16 * (8192 + 128) * sizeof(float);

    prep_kernel<<<dim3(32, 8, 3), dim3(256), 0, stream>>>(
        y, positions, Wq, Wk, Wv, coeff, pw, pb, Qh, Ql, Kh, Kl, Vh, Vl);

    if (ws_size >= base_bytes + 136 * per_slot) {
        float* rs_part = O_part + (size_t)136 * 16 * 8192;
        attn_kernel<2><<<dim3(136, 16), dim3(256), 0, stream>>>(
            Qh, Ql, Kh, Kl, Vh, Vl, O_part, rs_part);
        reduce_div_kernel<2><<<dim3(2048), dim3(256), 0, stream>>>(O_part, rs_part, out);
    } else if (ws_size >= base_bytes + 72 * per_slot) {
        float* rs_part = O_part + (size_t)72 * 16 * 8192;
        attn_kernel<4><<<dim3(72, 16), dim3(256), 0, stream>>>(
            Qh, Ql, Kh, Kl, Vh, Vl, O_part, rs_part);
        reduce_div_kernel<4><<<dim3(2048), dim3(256), 0, stream>>>(O_part, rs_part, out);
    } else {
        float* rs_part = O_part + (size_t)40 * 16 * 8192;
        attn_kernel<8><<<dim3(40, 16), dim3(256), 0, stream>>>(
            Qh, Ql, Kh, Kl, Vh, Vl, O_part, rs_part);
        reduce_div_kernel<8><<<dim3(2048), dim3(256), 0, stream>>>(O_part, rs_part, out);
    }
}

// Round 9
// 165.903 us; speedup vs baseline: 1.6355x; 1.2960x over previous
//
#include <hip/hip_runtime.h>
#include <hip/hip_bf16.h>

typedef __attribute__((ext_vector_type(8))) short bf16x8;
typedef __attribute__((ext_vector_type(4))) float f32x4;
typedef unsigned int u32;

#define L_SEQ 2048
#define NHEAD 8
#define DHEAD 64
#define DMODEL 512
#define QK_STRIDE 262144          // per-nh shorts, frag-major Q/K (2048*128)
#define V_STRIDE  131072          // per-nh shorts, frag-major V (2048*64)

__device__ __forceinline__ short f2bf(float f) {
    union { float f; unsigned u; } x; x.f = f;
    unsigned r = x.u + 0x7FFFu + ((x.u >> 16) & 1u);
    return (short)(r >> 16);
}

__device__ __forceinline__ void split1(float x, short& hi, short& lo) {
    unsigned uh = __float_as_uint(x) & 0xFFFF0000u;
    hi = (short)(uh >> 16);
    lo = f2bf(x - __uint_as_float(uh));
}

__device__ __forceinline__ void split8(const float* p, bf16x8& hi, bf16x8& lo) {
    #pragma unroll
    for (int i = 0; i < 8; ++i) {
        float x = p[i];
        unsigned uh = __float_as_uint(x) & 0xFFFF0000u;
        hi[i] = (short)(uh >> 16);
        lo[i] = f2bf(x - __uint_as_float(uh));
    }
}

__device__ __forceinline__ u32 cvtpk_bf16(float a, float b) {
    u32 r;
    asm("v_cvt_pk_bf16_f32 %0, %1, %2" : "=v"(r) : "v"(a), "v"(b));
    return r;
}

// async global->LDS, 16B per lane, wave-uniform LDS base (HW adds lane*16)
__device__ __forceinline__ void gload_lds16(const void* g, void* l) {
    __builtin_amdgcn_global_load_lds(
        (const __attribute__((address_space(1))) unsigned int*)g,
        (__attribute__((address_space(3))) unsigned int*)l, 16, 0, 0);
}

// ---------------------------------------------------------------------------
// Kernel 1: C = y @ W^T with split-bf16 3-term MFMA. Epilogues write
// FRAG-MAJOR layouts so attn loads/stages are 16B/lane coalesced (see R7).
// ---------------------------------------------------------------------------
__global__ __launch_bounds__(256) void prep_kernel(
    const float* __restrict__ y, const float* __restrict__ positions,
    const float* __restrict__ Wq, const float* __restrict__ Wk, const float* __restrict__ Wv,
    const float* __restrict__ coeff, const float* __restrict__ pw, const float* __restrict__ pb,
    short* __restrict__ Qh, short* __restrict__ Ql,
    short* __restrict__ Kh, short* __restrict__ Kl,
    short* __restrict__ Vh, short* __restrict__ Vl)
{
    __shared__ float vtile[128][65];
    const int mode = blockIdx.z;
    const float* W = (mode == 0) ? Wq : (mode == 1) ? Wk : Wv;
    const int m_base = blockIdx.x * 128;
    const int h = blockIdx.y;
    const int n_base = h * 64;
    const int tid = threadIdx.x;
    const int lane = tid & 63;
    const int wv = tid >> 6;
    const int lr = lane & 15;
    const int lg = lane >> 4;

    f32x4 acc[2][4];
    #pragma unroll
    for (int t = 0; t < 2; ++t)
        #pragma unroll
        for (int c = 0; c < 4; ++c) acc[t][c] = (f32x4){0.f, 0.f, 0.f, 0.f};

    for (int kk = 0; kk < DMODEL; kk += 32) {
        bf16x8 ah[2], al[2], bh[4], bl[4];
        #pragma unroll
        for (int t = 0; t < 2; ++t) {
            const float* src = y + (size_t)(m_base + wv*32 + t*16 + lr) * DMODEL + kk + lg*8;
            float tmp[8];
            *(float4*)tmp       = *(const float4*)src;
            *(float4*)(tmp + 4) = *(const float4*)(src + 4);
            split8(tmp, ah[t], al[t]);
        }
        #pragma unroll
        for (int c = 0; c < 4; ++c) {
            const float* src = W + (size_t)(n_base + c*16 + lr) * DMODEL + kk + lg*8;
            float tmp[8];
            *(float4*)tmp       = *(const float4*)src;
            *(float4*)(tmp + 4) = *(const float4*)(src + 4);
            split8(tmp, bh[c], bl[c]);
        }
        #pragma unroll
        for (int t = 0; t < 2; ++t)
            #pragma unroll
            for (int c = 0; c < 4; ++c) {
                acc[t][c] = __builtin_amdgcn_mfma_f32_16x16x32_bf16(ah[t], bh[c], acc[t][c], 0, 0, 0);
                acc[t][c] = __builtin_amdgcn_mfma_f32_16x16x32_bf16(ah[t], bl[c], acc[t][c], 0, 0, 0);
                acc[t][c] = __builtin_amdgcn_mfma_f32_16x16x32_bf16(al[t], bh[c], acc[t][c], 0, 0, 0);
            }
    }

    const int n_idx = m_base >> 11;
    const int nh = n_idx * NHEAD + h;

    if (mode == 2) {
        #pragma unroll
        for (int t = 0; t < 2; ++t)
            #pragma unroll
            for (int c = 0; c < 4; ++c)
                #pragma unroll
                for (int r = 0; r < 4; ++r)
                    vtile[wv*32 + t*16 + lg*4 + r][c*16 + lr] = acc[t][c][r];
        __syncthreads();
        const size_t vbase = (size_t)nh * V_STRIDE;
        #pragma unroll
        for (int i = 0; i < 32; ++i) {
            const int key_l = (tid & 7) + 8*(i & 15);          // 0..127
            const int d     = (tid >> 3) + 32*(i >> 4);        // 0..63
            const int key   = (m_base & (L_SEQ - 1)) + key_l;
            short th, tl;
            split1(vtile[key_l][d], th, tl);
            const size_t idx = vbase +
                ((size_t)((key >> 5)*4 + (d >> 4))*64 + (d & 15) + 16*((key >> 3) & 3))*8 + (key & 7);
            Vh[idx] = th; Vl[idx] = tl;
        }
    } else {
        short* OUTh = (mode == 0) ? Qh : Kh;
        short* OUTl = (mode == 0) ? Ql : Kl;
        const size_t qbase_nh = (size_t)nh * QK_STRIDE;
        #pragma unroll
        for (int t = 0; t < 2; ++t) {
            #pragma unroll
            for (int c = 0; c < 4; ++c) {
                const int d = c*16 + lr;
                const float pwv = pw[n_base + d];
                const float pbv = pb[n_base + d];
                const float cf  = (mode == 0) ? coeff[n_base + d] : 1.0f;
                const int lane_t = 16*((2*c + (lr >> 3)) & 3);
                const int j = lr & 7;
                #pragma unroll
                for (int r = 0; r < 4; ++r) {
                    const int gm = m_base + wv*32 + t*16 + lg*4 + r;
                    const int l = gm & (L_SEQ - 1);
                    const int B = l >> 4;
                    const float posv = positions[gm];
                    const float x = acc[t][c][r];
                    const float sp = fmaxf(x, 0.f) + __logf(1.f + __expf(-fabsf(x)));
                    const float p = pwv * posv + pbv;
                    const float cs = __cosf(p), sn = __sinf(p);
                    short h1, l1, h2, l2;
                    split1(sp * cf * cs, h1, l1);
                    split1(sp * cf * sn, h2, l2);
                    const int ln = (l & 15) + lane_t;
                    const size_t idx_c = qbase_nh + ((size_t)(B*4 + (c >> 1))*64 + ln)*8 + j;
                    const size_t idx_s = qbase_nh + ((size_t)(B*4 + 2 + (c >> 1))*64 + ln)*8 + j;
                    OUTh[idx_c] = h1; OUTl[idx_c] = l1;
                    OUTh[idx_s] = h2; OUTl[idx_s] = l2;
                }
            }
        }
    }
}

// ---------------------------------------------------------------------------
// Kernel 2: split-K causal attention. R9: K/V staged per k-step into LDS via
// global_load_lds (48KB: K-hi 16K | K-lo 16K | V-hi 8K | V-lo 8K) — removes
// the 48-serialized-global-load chain R8 exposed (VGPR=108 proved compiler
// sank loads; ~600cy each). MFMAs feed from ds_read_b128. Swapped QK (S^T),
// PV A-frags via ds_bpermute. Uniform CHUNK-kstep blocks, partial slabs.
// ---------------------------------------------------------------------------
template<int CHUNK>
__global__ __launch_bounds__(256) void attn_kernel(
    const short* __restrict__ Qh, const short* __restrict__ Ql,
    const short* __restrict__ Kh, const short* __restrict__ Kl,
    const short* __restrict__ Vh, const short* __restrict__ Vl,
    float* __restrict__ O_part, float* __restrict__ rs_part)
{
    __shared__ char s_lds[49152];
    // map blockIdx.x (chunk slot) -> (qt, chunk index)
    int rem = blockIdx.x, qt = 0;
    for (qt = 0; qt < 16; ++qt) {
        const int nch = (2*qt + 2 + CHUNK - 1) / CHUNK;
        if (rem < nch) break;
        rem -= nch;
    }
    const int nst = 2*qt + 2;
    const int kt0 = rem * CHUNK;
    const int kt1 = (kt0 + CHUNK < nst) ? (kt0 + CHUNK) : nst;

    const int nh = blockIdx.y;
    const int q_base = qt * 128;
    const int tid = threadIdx.x;
    const int lane = tid & 63;
    const int wv = tid >> 6;
    const int lr = lane & 15;
    const int lg = lane >> 4;

    const short* Qh_b = Qh + (size_t)nh * QK_STRIDE;
    const short* Ql_b = Ql + (size_t)nh * QK_STRIDE;
    const short* Kh_b = Kh + (size_t)nh * QK_STRIDE;
    const short* Kl_b = Kl + (size_t)nh * QK_STRIDE;
    const short* Vh_b = Vh + (size_t)nh * V_STRIDE;
    const short* Vl_b = Vl + (size_t)nh * V_STRIDE;

    // Q fragments (B-operand), hoisted (independent loads -> batched).
    bf16x8 qh[2][4], ql[2][4];
    #pragma unroll
    for (int t = 0; t < 2; ++t) {
        const int Bq = qt*8 + wv*2 + t;
        #pragma unroll
        for (int kh = 0; kh < 4; ++kh) {
            const size_t off = ((size_t)(Bq*4 + kh)*64 + lane)*8;
            qh[t][kh] = *(const bf16x8*)(Qh_b + off);
            ql[t][kh] = *(const bf16x8*)(Ql_b + off);
        }
    }

    f32x4 o_acc[2][4];
    float rs[2];
    #pragma unroll
    for (int t = 0; t < 2; ++t) {
        #pragma unroll
        for (int c = 0; c < 4; ++c) o_acc[t][c] = (f32x4){0.f, 0.f, 0.f, 0.f};
        rs[t] = 0.f;
    }

    const int addr0 = (lr + ((lg & 1) * 2) * 16) << 2;
    const int addr1 = addr0 + 64;
    const bool selhi = (lg >= 2);
    const int lb = lane << 4;          // lane byte offset within a 1KB chunk

    for (int kt = kt0; kt < kt1; ++kt) {
        // ---- stage K/V tiles for this kstep into LDS (DMA, no VGPRs) ----
        {
            const char* kh_src = (const char*)(Kh_b + (size_t)kt*8192);
            const char* kl_src = (const char*)(Kl_b + (size_t)kt*8192);
            const char* vh_src = (const char*)(Vh_b + (size_t)kt*4096);
            const char* vl_src = (const char*)(Vl_b + (size_t)kt*4096);
            #pragma unroll
            for (int i = 0; i < 12; ++i) {
                const int ch = wv*12 + i;                 // wave-uniform 0..47
                const char* src;
                if (ch < 16)      src = kh_src + ch*1024;
                else if (ch < 32) src = kl_src + (ch-16)*1024;
                else if (ch < 40) src = vh_src + (ch-32)*1024;
                else              src = vl_src + (ch-40)*1024;
                gload_lds16(src + lb, s_lds + ch*1024);
            }
        }
        __syncthreads();   // drains vmcnt -> staged data visible

        // ---- QK^T (swapped): st[t][c] = S^T fragments, K from LDS ----
        f32x4 st[2][4];
        #pragma unroll
        for (int t = 0; t < 2; ++t)
            #pragma unroll
            for (int c = 0; c < 4; ++c) st[t][c] = (f32x4){0.f, 0.f, 0.f, 0.f};

        #pragma unroll
        for (int c = 0; c < 4; ++c) {
            #pragma unroll
            for (int kh = 0; kh < 4; ++kh) {
                const int boff = (c*4 + kh)*1024 + lb;
                const bf16x8 kfh = *(const bf16x8*)(s_lds + boff);
                const bf16x8 kfl = *(const bf16x8*)(s_lds + 16384 + boff);
                #pragma unroll
                for (int t = 0; t < 2; ++t) {
                    st[t][c] = __builtin_amdgcn_mfma_f32_16x16x32_bf16(kfh, qh[t][kh], st[t][c], 0, 0, 0);
                    st[t][c] = __builtin_amdgcn_mfma_f32_16x16x32_bf16(kfh, ql[t][kh], st[t][c], 0, 0, 0);
                    st[t][c] = __builtin_amdgcn_mfma_f32_16x16x32_bf16(kfl, qh[t][kh], st[t][c], 0, 0, 0);
                }
            }
        }

        // ---- mask + rowsum (in-register) ----
        const int k0 = kt * 64;
        const bool domask = (kt >= 2*qt);
        #pragma unroll
        for (int t = 0; t < 2; ++t) {
            const int gq = q_base + wv*32 + t*16 + lr;
            float part = 0.f;
            #pragma unroll
            for (int c = 0; c < 4; ++c)
                #pragma unroll
                for (int r = 0; r < 4; ++r) {
                    const int gk = k0 + c*16 + lg*4 + r;
                    float v = st[t][c][r];
                    if (domask && gk > gq) v = 0.f;
                    st[t][c][r] = v;
                    part += v;
                }
            part += __shfl_xor(part, 16);
            part += __shfl_xor(part, 32);
            rs[t] += part;
        }

        // ---- pack S^T to bf16 hi/lo words ----
        u32 pwh[2][4][2], pwl[2][4][2];
        #pragma unroll
        for (int t = 0; t < 2; ++t)
            #pragma unroll
            for (int c = 0; c < 4; ++c) {
                const u32 b0 = __float_as_uint(st[t][c][0]);
                const u32 b1 = __float_as_uint(st[t][c][1]);
                const u32 b2 = __float_as_uint(st[t][c][2]);
                const u32 b3 = __float_as_uint(st[t][c][3]);
                pwh[t][c][0] = (b1 & 0xFFFF0000u) | (b0 >> 16);
                pwh[t][c][1] = (b3 & 0xFFFF0000u) | (b2 >> 16);
                const float l0 = st[t][c][0] - __uint_as_float(b0 & 0xFFFF0000u);
                const float l1 = st[t][c][1] - __uint_as_float(b1 & 0xFFFF0000u);
                const float l2 = st[t][c][2] - __uint_as_float(b2 & 0xFFFF0000u);
                const float l3 = st[t][c][3] - __uint_as_float(b3 & 0xFFFF0000u);
                pwl[t][c][0] = cvtpk_bf16(l0, l1);
                pwl[t][c][1] = cvtpk_bf16(l2, l3);
            }

        // ---- PV: gather PA frags via bpermute, V frags from LDS ----
        #pragma unroll
        for (int kc = 0; kc < 2; ++kc) {
            union { u32 u[4]; bf16x8 v; } pah[2], pal[2];
            #pragma unroll
            for (int t = 0; t < 2; ++t) {
                u32 a, b;
                a = (u32)__builtin_amdgcn_ds_bpermute(addr0, (int)pwh[t][2*kc][0]);
                b = (u32)__builtin_amdgcn_ds_bpermute(addr0, (int)pwh[t][2*kc+1][0]);
                pah[t].u[0] = selhi ? b : a;
                a = (u32)__builtin_amdgcn_ds_bpermute(addr0, (int)pwh[t][2*kc][1]);
                b = (u32)__builtin_amdgcn_ds_bpermute(addr0, (int)pwh[t][2*kc+1][1]);
                pah[t].u[1] = selhi ? b : a;
                a = (u32)__builtin_amdgcn_ds_bpermute(addr1, (int)pwh[t][2*kc][0]);
                b = (u32)__builtin_amdgcn_ds_bpermute(addr1, (int)pwh[t][2*kc+1][0]);
                pah[t].u[2] = selhi ? b : a;
                a = (u32)__builtin_amdgcn_ds_bpermute(addr1, (int)pwh[t][2*kc][1]);
                b = (u32)__builtin_amdgcn_ds_bpermute(addr1, (int)pwh[t][2*kc+1][1]);
                pah[t].u[3] = selhi ? b : a;

                a = (u32)__builtin_amdgcn_ds_bpermute(addr0, (int)pwl[t][2*kc][0]);
                b = (u32)__builtin_amdgcn_ds_bpermute(addr0, (int)pwl[t][2*kc+1][0]);
                pal[t].u[0] = selhi ? b : a;
                a = (u32)__builtin_amdgcn_ds_bpermute(addr0, (int)pwl[t][2*kc][1]);
                b = (u32)__builtin_amdgcn_ds_bpermute(addr0, (int)pwl[t][2*kc+1][1]);
                pal[t].u[1] = selhi ? b : a;
                a = (u32)__builtin_amdgcn_ds_bpermute(addr1, (int)pwl[t][2*kc][0]);
                b = (u32)__builtin_amdgcn_ds_bpermute(addr1, (int)pwl[t][2*kc+1][0]);
                pal[t].u[2] = selhi ? b : a;
                a = (u32)__builtin_amdgcn_ds_bpermute(addr1, (int)pwl[t][2*kc][1]);
                b = (u32)__builtin_amdgcn_ds_bpermute(addr1, (int)pwl[t][2*kc+1][1]);
                pal[t].u[3] = selhi ? b : a;
            }
            #pragma unroll
            for (int cd = 0; cd < 4; ++cd) {
                const int voff = (kc*4 + cd)*1024 + lb;
                const bf16x8 vfh = *(const bf16x8*)(s_lds + 32768 + voff);
                const bf16x8 vfl = *(const bf16x8*)(s_lds + 40960 + voff);
                #pragma unroll
                for (int t = 0; t < 2; ++t) {
                    o_acc[t][cd] = __builtin_amdgcn_mfma_f32_16x16x32_bf16(pah[t].v, vfh, o_acc[t][cd], 0, 0, 0);
                    o_acc[t][cd] = __builtin_amdgcn_mfma_f32_16x16x32_bf16(pah[t].v, vfl, o_acc[t][cd], 0, 0, 0);
                    o_acc[t][cd] = __builtin_amdgcn_mfma_f32_16x16x32_bf16(pal[t].v, vfh, o_acc[t][cd], 0, 0, 0);
                }
            }
        }
        __syncthreads();   // all waves done reading before next-kstep overwrite
    }

    // ---- write partials (no atomics) ----
    const size_t slab = (size_t)blockIdx.x * 16 + nh;
    #pragma unroll
    for (int t = 0; t < 2; ++t)
        if (lg == 0)
            rs_part[slab*128 + wv*32 + t*16 + lr] = rs[t];

    #pragma unroll
    for (int t = 0; t < 2; ++t)
        #pragma unroll
        for (int cd = 0; cd < 4; ++cd)
            #pragma unroll
            for (int r = 0; r < 4; ++r) {
                const int row = wv*32 + t*16 + lg*4 + r;
                O_part[slab*8192 + row*64 + cd*16 + lr] = o_acc[t][cd][r];
            }
}

// Reduce chunk partials per (nh,qt), divide by rowsum, write output.
template<int CHUNK>
__global__ __launch_bounds__(256) void reduce_div_kernel(
    const float* __restrict__ O_part, const float* __restrict__ rs_part,
    float* __restrict__ out)
{
    const int idx = blockIdx.x * 256 + threadIdx.x;   // 512K threads
    const int d4 = idx & 15;
    const int l  = (idx >> 4) & (L_SEQ - 1);
    const int nh = idx >> 15;
    const int qt = l >> 7;
    const int row = l & 127;
    int cs = 0;
    for (int q = 0; q < qt; ++q) cs += (2*q + 2 + CHUNK - 1) / CHUNK;
    const int nch = (2*qt + 2 + CHUNK - 1) / CHUNK;

    float4 o = {0.f, 0.f, 0.f, 0.f};
    float rssum = 0.f;
    for (int ci = 0; ci < nch; ++ci) {
        const size_t slab = (size_t)(cs + ci) * 16 + nh;
        const float4 p = *(const float4*)(O_part + slab*8192 + row*64 + d4*4);
        o.x += p.x; o.y += p.y; o.z += p.z; o.w += p.w;
        rssum += rs_part[slab*128 + row];
    }
    const float inv = 1.0f / rssum;
    float4 r;
    r.x = o.x * inv; r.y = o.y * inv; r.z = o.z * inv; r.w = o.w * inv;
    const int n = nh >> 3, h = nh & 7;
    *(float4*)(out + ((size_t)(n*L_SEQ + l))*DMODEL + h*DHEAD + d4*4) = r;
}

extern "C" void kernel_launch(void* const* d_in, const int* in_sizes, int n_in,
                              void* d_out, int out_size, void* d_ws, size_t ws_size,
                              hipStream_t stream) {
    const float* y         = (const float*)d_in[0];
    const float* positions = (const float*)d_in[1];
    const float* Wq        = (const float*)d_in[2];
    const float* Wk        = (const float*)d_in[3];
    const float* Wv        = (const float*)d_in[4];
    const float* coeff     = (const float*)d_in[5];
    const float* pw        = (const float*)d_in[6];
    const float* pb        = (const float*)d_in[7];
    float* out = (float*)d_out;

    const size_t SQK = (size_t)16 * QK_STRIDE;   // shorts
    const size_t SV  = (size_t)16 * V_STRIDE;
    short* Qh = (short*)d_ws;
    short* Ql = Qh + SQK;
    short* Kh = Ql + SQK;
    short* Kl = Kh + SQK;
    short* Vh = Kl + SQK;
    short* Vl = Vh + SV;
    float* O_part = (float*)(Vl + SV);
    const size_t base_bytes = (SQK*4 + SV*2) * sizeof(short);
    const size_t per_slot   = (size_t)16 * (8192 + 128) * sizeof(float);

    prep_kernel<<<dim3(32, 8, 3), dim3(256), 0, stream>>>(
        y, positions, Wq, Wk, Wv, coeff, pw, pb, Qh, Ql, Kh, Kl, Vh, Vl);

    if (ws_size >= base_bytes + 136 * per_slot) {
        float* rs_part = O_part + (size_t)136 * 16 * 8192;
        attn_kernel<2><<<dim3(136, 16), dim3(256), 0, stream>>>(
            Qh, Ql, Kh, Kl, Vh, Vl, O_part, rs_part);
        reduce_div_kernel<2><<<dim3(2048), dim3(256), 0, stream>>>(O_part, rs_part, out);
    } else if (ws_size >= base_bytes + 72 * per_slot) {
        float* rs_part = O_part + (size_t)72 * 16 * 8192;
        attn_kernel<4><<<dim3(72, 16), dim3(256), 0, stream>>>(
            Qh, Ql, Kh, Kl, Vh, Vl, O_part, rs_part);
        reduce_div_kernel<4><<<dim3(2048), dim3(256), 0, stream>>>(O_part, rs_part, out);
    } else {
        float* rs_part = O_part + (size_t)40 * 16 * 8192;
        attn_kernel<8><<<dim3(40, 16), dim3(256), 0, stream>>>(
            Qh, Ql, Kh, Kl, Vh, Vl, O_part, rs_part);
        reduce_div_kernel<8><<<dim3(2048), dim3(256), 0, stream>>>(O_part, rs_part, out);
    }
}

// Round 10
// 124.859 us; speedup vs baseline: 2.1731x; 1.3287x over previous
//
#include <hip/hip_runtime.h>
#include <hip/hip_bf16.h>

typedef __attribute__((ext_vector_type(8))) short bf16x8;
typedef __attribute__((ext_vector_type(4))) float f32x4;
typedef unsigned int u32;

#define L_SEQ 2048
#define NHEAD 8
#define DHEAD 64
#define DMODEL 512
#define QK_STRIDE 262144          // per-nh shorts, frag-major Q/K (2048*128)
#define V_STRIDE  131072          // per-nh shorts, frag-major V (2048*64)

__device__ __forceinline__ short f2bf(float f) {
    union { float f; unsigned u; } x; x.f = f;
    unsigned r = x.u + 0x7FFFu + ((x.u >> 16) & 1u);
    return (short)(r >> 16);
}

__device__ __forceinline__ void split1(float x, short& hi, short& lo) {
    unsigned uh = __float_as_uint(x) & 0xFFFF0000u;
    hi = (short)(uh >> 16);
    lo = f2bf(x - __uint_as_float(uh));
}

__device__ __forceinline__ void split8(const float* p, bf16x8& hi, bf16x8& lo) {
    #pragma unroll
    for (int i = 0; i < 8; ++i) {
        float x = p[i];
        unsigned uh = __float_as_uint(x) & 0xFFFF0000u;
        hi[i] = (short)(uh >> 16);
        lo[i] = f2bf(x - __uint_as_float(uh));
    }
}

__device__ __forceinline__ u32 cvtpk_bf16(float a, float b) {
    u32 r;
    asm("v_cvt_pk_bf16_f32 %0, %1, %2" : "=v"(r) : "v"(a), "v"(b));
    return r;
}

// async global->LDS, 16B per lane, wave-uniform LDS base (HW adds lane*16)
__device__ __forceinline__ void gload_lds16(const void* g, void* l) {
    __builtin_amdgcn_global_load_lds(
        (const __attribute__((address_space(1))) unsigned int*)g,
        (__attribute__((address_space(3))) unsigned int*)l, 16, 0, 0);
}

// ---------------------------------------------------------------------------
// Kernel 0: one-time split of y / W into frag-major bf16 hi/lo arrays.
// Unit u (one per wave): u<4096 -> y row-block B=u>>4, k-block kb=u&15;
// else W: u2=u-4096, mat=u2>>9, C=(u2>>4)&31, kb=u2&15.
// Frag layout: ((B*16+kb)*64 + lane)*8 + j, lane=(row&15)+16*((k>>3)&3).
// Kills the 24x-redundant in-loop split VALU that made prep 85us (R9).
// ---------------------------------------------------------------------------
__global__ __launch_bounds__(256) void split_kernel(
    const float* __restrict__ y,
    const float* __restrict__ Wq, const float* __restrict__ Wk, const float* __restrict__ Wv,
    short* __restrict__ yh, short* __restrict__ yl,
    short* __restrict__ wh, short* __restrict__ wl)
{
    const int wv = threadIdx.x >> 6, ln = threadIdx.x & 63;
    const int u = blockIdx.x * 4 + wv;          // 0..5631
    float tmp[8];
    if (u < 4096) {
        const int B = u >> 4, kb = u & 15;
        const int row = B*16 + (ln & 15);
        const int k   = kb*32 + (ln >> 4)*8;
        const float* src = y + (size_t)row * DMODEL + k;
        *(float4*)tmp       = *(const float4*)src;
        *(float4*)(tmp + 4) = *(const float4*)(src + 4);
        bf16x8 hi, lo;
        split8(tmp, hi, lo);
        const size_t dst = (size_t)u*512 + ln*8;
        *(bf16x8*)(yh + dst) = hi;
        *(bf16x8*)(yl + dst) = lo;
    } else {
        const int u2 = u - 4096;                // 0..1535
        const int mat = u2 >> 9;
        const int r   = u2 & 511;
        const int C = r >> 4, kb = r & 15;
        const float* W = (mat == 0) ? Wq : (mat == 1) ? Wk : Wv;
        const int col = C*16 + (ln & 15);
        const int k   = kb*32 + (ln >> 4)*8;
        const float* src = W + (size_t)col * DMODEL + k;
        *(float4*)tmp       = *(const float4*)src;
        *(float4*)(tmp + 4) = *(const float4*)(src + 4);
        bf16x8 hi, lo;
        split8(tmp, hi, lo);
        const size_t dst = (size_t)u2*512 + ln*8;
        *(bf16x8*)(wh + dst) = hi;
        *(bf16x8*)(wl + dst) = lo;
    }
}

// ---------------------------------------------------------------------------
// Kernel 1: C = y @ W^T, pure bf16 3-term MFMA from pre-split frag-major
// arrays (no in-loop conversion VALU). Epilogues write FRAG-MAJOR layouts
// for attn (see R7). Block: 128 rows x 64 cols (one head), 4 waves.
// Grid (32, 8, 3).
// ---------------------------------------------------------------------------
__global__ __launch_bounds__(256) void prep_kernel(
    const short* __restrict__ yh, const short* __restrict__ yl,
    const short* __restrict__ wh, const short* __restrict__ wl,
    const float* __restrict__ positions,
    const float* __restrict__ coeff, const float* __restrict__ pw, const float* __restrict__ pb,
    short* __restrict__ Qh, short* __restrict__ Ql,
    short* __restrict__ Kh, short* __restrict__ Kl,
    short* __restrict__ Vh, short* __restrict__ Vl)
{
    __shared__ float vtile[128][65];
    const int mode = blockIdx.z;
    const int m_base = blockIdx.x * 128;
    const int h = blockIdx.y;
    const int n_base = h * 64;
    const int tid = threadIdx.x;
    const int lane = tid & 63;
    const int wv = tid >> 6;
    const int lr = lane & 15;
    const int lg = lane >> 4;

    const short* whm = wh + (size_t)mode * 262144;
    const short* wlm = wl + (size_t)mode * 262144;
    const int Ba0 = blockIdx.x*8 + wv*2;

    f32x4 acc[2][4];
    #pragma unroll
    for (int t = 0; t < 2; ++t)
        #pragma unroll
        for (int c = 0; c < 4; ++c) acc[t][c] = (f32x4){0.f, 0.f, 0.f, 0.f};

    #pragma unroll 4
    for (int kb = 0; kb < 16; ++kb) {
        bf16x8 ah[2], al[2], bh[4], bl[4];
        #pragma unroll
        for (int t = 0; t < 2; ++t) {
            const size_t off = ((size_t)((Ba0 + t)*16 + kb)*64 + lane)*8;
            ah[t] = *(const bf16x8*)(yh + off);
            al[t] = *(const bf16x8*)(yl + off);
        }
        #pragma unroll
        for (int c = 0; c < 4; ++c) {
            const size_t off = ((size_t)((h*4 + c)*16 + kb)*64 + lane)*8;
            bh[c] = *(const bf16x8*)(whm + off);
            bl[c] = *(const bf16x8*)(wlm + off);
        }
        #pragma unroll
        for (int t = 0; t < 2; ++t)
            #pragma unroll
            for (int c = 0; c < 4; ++c) {
                acc[t][c] = __builtin_amdgcn_mfma_f32_16x16x32_bf16(ah[t], bh[c], acc[t][c], 0, 0, 0);
                acc[t][c] = __builtin_amdgcn_mfma_f32_16x16x32_bf16(ah[t], bl[c], acc[t][c], 0, 0, 0);
                acc[t][c] = __builtin_amdgcn_mfma_f32_16x16x32_bf16(al[t], bh[c], acc[t][c], 0, 0, 0);
            }
    }

    const int n_idx = m_base >> 11;
    const int nh = n_idx * NHEAD + h;

    if (mode == 2) {
        #pragma unroll
        for (int t = 0; t < 2; ++t)
            #pragma unroll
            for (int c = 0; c < 4; ++c)
                #pragma unroll
                for (int r = 0; r < 4; ++r)
                    vtile[wv*32 + t*16 + lg*4 + r][c*16 + lr] = acc[t][c][r];
        __syncthreads();
        const size_t vbase = (size_t)nh * V_STRIDE;
        #pragma unroll
        for (int i = 0; i < 32; ++i) {
            const int key_l = (tid & 7) + 8*(i & 15);          // 0..127
            const int d     = (tid >> 3) + 32*(i >> 4);        // 0..63
            const int key   = (m_base & (L_SEQ - 1)) + key_l;
            short th, tl;
            split1(vtile[key_l][d], th, tl);
            const size_t idx = vbase +
                ((size_t)((key >> 5)*4 + (d >> 4))*64 + (d & 15) + 16*((key >> 3) & 3))*8 + (key & 7);
            Vh[idx] = th; Vl[idx] = tl;
        }
    } else {
        short* OUTh = (mode == 0) ? Qh : Kh;
        short* OUTl = (mode == 0) ? Ql : Kl;
        const size_t qbase_nh = (size_t)nh * QK_STRIDE;
        #pragma unroll
        for (int t = 0; t < 2; ++t) {
            #pragma unroll
            for (int c = 0; c < 4; ++c) {
                const int d = c*16 + lr;
                const float pwv = pw[n_base + d];
                const float pbv = pb[n_base + d];
                const float cf  = (mode == 0) ? coeff[n_base + d] : 1.0f;
                const int lane_t = 16*((2*c + (lr >> 3)) & 3);
                const int j = lr & 7;
                #pragma unroll
                for (int r = 0; r < 4; ++r) {
                    const int gm = m_base + wv*32 + t*16 + lg*4 + r;
                    const int l = gm & (L_SEQ - 1);
                    const int B = l >> 4;
                    const float posv = positions[gm];
                    const float x = acc[t][c][r];
                    const float sp = fmaxf(x, 0.f) + __logf(1.f + __expf(-fabsf(x)));
                    const float p = pwv * posv + pbv;
                    const float cs = __cosf(p), sn = __sinf(p);
                    short h1, l1, h2, l2;
                    split1(sp * cf * cs, h1, l1);
                    split1(sp * cf * sn, h2, l2);
                    const int ln = (l & 15) + lane_t;
                    const size_t idx_c = qbase_nh + ((size_t)(B*4 + (c >> 1))*64 + ln)*8 + j;
                    const size_t idx_s = qbase_nh + ((size_t)(B*4 + 2 + (c >> 1))*64 + ln)*8 + j;
                    OUTh[idx_c] = h1; OUTl[idx_c] = l1;
                    OUTh[idx_s] = h2; OUTl[idx_s] = l2;
                }
            }
        }
    }
}

// ---------------------------------------------------------------------------
// Kernel 2: split-K causal attention. K/V staged per k-step into LDS via
// global_load_lds (48KB). Swapped QK (S^T), PV A-frags via ds_bpermute.
// Uniform CHUNK-kstep blocks, partial slabs. (R9 structure, unchanged.)
// ---------------------------------------------------------------------------
template<int CHUNK>
__global__ __launch_bounds__(256) void attn_kernel(
    const short* __restrict__ Qh, const short* __restrict__ Ql,
    const short* __restrict__ Kh, const short* __restrict__ Kl,
    const short* __restrict__ Vh, const short* __restrict__ Vl,
    float* __restrict__ O_part, float* __restrict__ rs_part)
{
    __shared__ char s_lds[49152];
    int rem = blockIdx.x, qt = 0;
    for (qt = 0; qt < 16; ++qt) {
        const int nch = (2*qt + 2 + CHUNK - 1) / CHUNK;
        if (rem < nch) break;
        rem -= nch;
    }
    const int nst = 2*qt + 2;
    const int kt0 = rem * CHUNK;
    const int kt1 = (kt0 + CHUNK < nst) ? (kt0 + CHUNK) : nst;

    const int nh = blockIdx.y;
    const int q_base = qt * 128;
    const int tid = threadIdx.x;
    const int lane = tid & 63;
    const int wv = tid >> 6;
    const int lr = lane & 15;
    const int lg = lane >> 4;

    const short* Qh_b = Qh + (size_t)nh * QK_STRIDE;
    const short* Ql_b = Ql + (size_t)nh * QK_STRIDE;
    const short* Kh_b = Kh + (size_t)nh * QK_STRIDE;
    const short* Kl_b = Kl + (size_t)nh * QK_STRIDE;
    const short* Vh_b = Vh + (size_t)nh * V_STRIDE;
    const short* Vl_b = Vl + (size_t)nh * V_STRIDE;

    bf16x8 qh[2][4], ql[2][4];
    #pragma unroll
    for (int t = 0; t < 2; ++t) {
        const int Bq = qt*8 + wv*2 + t;
        #pragma unroll
        for (int kh = 0; kh < 4; ++kh) {
            const size_t off = ((size_t)(Bq*4 + kh)*64 + lane)*8;
            qh[t][kh] = *(const bf16x8*)(Qh_b + off);
            ql[t][kh] = *(const bf16x8*)(Ql_b + off);
        }
    }

    f32x4 o_acc[2][4];
    float rs[2];
    #pragma unroll
    for (int t = 0; t < 2; ++t) {
        #pragma unroll
        for (int c = 0; c < 4; ++c) o_acc[t][c] = (f32x4){0.f, 0.f, 0.f, 0.f};
        rs[t] = 0.f;
    }

    const int addr0 = (lr + ((lg & 1) * 2) * 16) << 2;
    const int addr1 = addr0 + 64;
    const bool selhi = (lg >= 2);
    const int lb = lane << 4;

    for (int kt = kt0; kt < kt1; ++kt) {
        {
            const char* kh_src = (const char*)(Kh_b + (size_t)kt*8192);
            const char* kl_src = (const char*)(Kl_b + (size_t)kt*8192);
            const char* vh_src = (const char*)(Vh_b + (size_t)kt*4096);
            const char* vl_src = (const char*)(Vl_b + (size_t)kt*4096);
            #pragma unroll
            for (int i = 0; i < 12; ++i) {
                const int ch = wv*12 + i;
                const char* src;
                if (ch < 16)      src = kh_src + ch*1024;
                else if (ch < 32) src = kl_src + (ch-16)*1024;
                else if (ch < 40) src = vh_src + (ch-32)*1024;
                else              src = vl_src + (ch-40)*1024;
                gload_lds16(src + lb, s_lds + ch*1024);
            }
        }
        __syncthreads();

        f32x4 st[2][4];
        #pragma unroll
        for (int t = 0; t < 2; ++t)
            #pragma unroll
            for (int c = 0; c < 4; ++c) st[t][c] = (f32x4){0.f, 0.f, 0.f, 0.f};

        #pragma unroll
        for (int c = 0; c < 4; ++c) {
            #pragma unroll
            for (int kh = 0; kh < 4; ++kh) {
                const int boff = (c*4 + kh)*1024 + lb;
                const bf16x8 kfh = *(const bf16x8*)(s_lds + boff);
                const bf16x8 kfl = *(const bf16x8*)(s_lds + 16384 + boff);
                #pragma unroll
                for (int t = 0; t < 2; ++t) {
                    st[t][c] = __builtin_amdgcn_mfma_f32_16x16x32_bf16(kfh, qh[t][kh], st[t][c], 0, 0, 0);
                    st[t][c] = __builtin_amdgcn_mfma_f32_16x16x32_bf16(kfh, ql[t][kh], st[t][c], 0, 0, 0);
                    st[t][c] = __builtin_amdgcn_mfma_f32_16x16x32_bf16(kfl, qh[t][kh], st[t][c], 0, 0, 0);
                }
            }
        }

        const int k0 = kt * 64;
        const bool domask = (kt >= 2*qt);
        #pragma unroll
        for (int t = 0; t < 2; ++t) {
            const int gq = q_base + wv*32 + t*16 + lr;
            float part = 0.f;
            #pragma unroll
            for (int c = 0; c < 4; ++c)
                #pragma unroll
                for (int r = 0; r < 4; ++r) {
                    const int gk = k0 + c*16 + lg*4 + r;
                    float v = st[t][c][r];
                    if (domask && gk > gq) v = 0.f;
                    st[t][c][r] = v;
                    part += v;
                }
            part += __shfl_xor(part, 16);
            part += __shfl_xor(part, 32);
            rs[t] += part;
        }

        u32 pwh[2][4][2], pwl[2][4][2];
        #pragma unroll
        for (int t = 0; t < 2; ++t)
            #pragma unroll
            for (int c = 0; c < 4; ++c) {
                const u32 b0 = __float_as_uint(st[t][c][0]);
                const u32 b1 = __float_as_uint(st[t][c][1]);
                const u32 b2 = __float_as_uint(st[t][c][2]);
                const u32 b3 = __float_as_uint(st[t][c][3]);
                pwh[t][c][0] = (b1 & 0xFFFF0000u) | (b0 >> 16);
                pwh[t][c][1] = (b3 & 0xFFFF0000u) | (b2 >> 16);
                const float l0 = st[t][c][0] - __uint_as_float(b0 & 0xFFFF0000u);
                const float l1 = st[t][c][1] - __uint_as_float(b1 & 0xFFFF0000u);
                const float l2 = st[t][c][2] - __uint_as_float(b2 & 0xFFFF0000u);
                const float l3 = st[t][c][3] - __uint_as_float(b3 & 0xFFFF0000u);
                pwl[t][c][0] = cvtpk_bf16(l0, l1);
                pwl[t][c][1] = cvtpk_bf16(l2, l3);
            }

        #pragma unroll
        for (int kc = 0; kc < 2; ++kc) {
            union { u32 u[4]; bf16x8 v; } pah[2], pal[2];
            #pragma unroll
            for (int t = 0; t < 2; ++t) {
                u32 a, b;
                a = (u32)__builtin_amdgcn_ds_bpermute(addr0, (int)pwh[t][2*kc][0]);
                b = (u32)__builtin_amdgcn_ds_bpermute(addr0, (int)pwh[t][2*kc+1][0]);
                pah[t].u[0] = selhi ? b : a;
                a = (u32)__builtin_amdgcn_ds_bpermute(addr0, (int)pwh[t][2*kc][1]);
                b = (u32)__builtin_amdgcn_ds_bpermute(addr0, (int)pwh[t][2*kc+1][1]);
                pah[t].u[1] = selhi ? b : a;
                a = (u32)__builtin_amdgcn_ds_bpermute(addr1, (int)pwh[t][2*kc][0]);
                b = (u32)__builtin_amdgcn_ds_bpermute(addr1, (int)pwh[t][2*kc+1][0]);
                pah[t].u[2] = selhi ? b : a;
                a = (u32)__builtin_amdgcn_ds_bpermute(addr1, (int)pwh[t][2*kc][1]);
                b = (u32)__builtin_amdgcn_ds_bpermute(addr1, (int)pwh[t][2*kc+1][1]);
                pah[t].u[3] = selhi ? b : a;

                a = (u32)__builtin_amdgcn_ds_bpermute(addr0, (int)pwl[t][2*kc][0]);
                b = (u32)__builtin_amdgcn_ds_bpermute(addr0, (int)pwl[t][2*kc+1][0]);
                pal[t].u[0] = selhi ? b : a;
                a = (u32)__builtin_amdgcn_ds_bpermute(addr0, (int)pwl[t][2*kc][1]);
                b = (u32)__builtin_amdgcn_ds_bpermute(addr0, (int)pwl[t][2*kc+1][1]);
                pal[t].u[1] = selhi ? b : a;
                a = (u32)__builtin_amdgcn_ds_bpermute(addr1, (int)pwl[t][2*kc][0]);
                b = (u32)__builtin_amdgcn_ds_bpermute(addr1, (int)pwl[t][2*kc+1][0]);
                pal[t].u[2] = selhi ? b : a;
                a = (u32)__builtin_amdgcn_ds_bpermute(addr1, (int)pwl[t][2*kc][1]);
                b = (u32)__builtin_amdgcn_ds_bpermute(addr1, (int)pwl[t][2*kc+1][1]);
                pal[t].u[3] = selhi ? b : a;
            }
            #pragma unroll
            for (int cd = 0; cd < 4; ++cd) {
                const int voff = (kc*4 + cd)*1024 + lb;
                const bf16x8 vfh = *(const bf16x8*)(s_lds + 32768 + voff);
                const bf16x8 vfl = *(const bf16x8*)(s_lds + 40960 + voff);
                #pragma unroll
                for (int t = 0; t < 2; ++t) {
                    o_acc[t][cd] = __builtin_amdgcn_mfma_f32_16x16x32_bf16(pah[t].v, vfh, o_acc[t][cd], 0, 0, 0);
                    o_acc[t][cd] = __builtin_amdgcn_mfma_f32_16x16x32_bf16(pah[t].v, vfl, o_acc[t][cd], 0, 0, 0);
                    o_acc[t][cd] = __builtin_amdgcn_mfma_f32_16x16x32_bf16(pal[t].v, vfh, o_acc[t][cd], 0, 0, 0);
                }
            }
        }
        __syncthreads();
    }

    const size_t slab = (size_t)blockIdx.x * 16 + nh;
    #pragma unroll
    for (int t = 0; t < 2; ++t)
        if (lg == 0)
            rs_part[slab*128 + wv*32 + t*16 + lr] = rs[t];

    #pragma unroll
    for (int t = 0; t < 2; ++t)
        #pragma unroll
        for (int cd = 0; cd < 4; ++cd)
            #pragma unroll
            for (int r = 0; r < 4; ++r) {
                const int row = wv*32 + t*16 + lg*4 + r;
                O_part[slab*8192 + row*64 + cd*16 + lr] = o_acc[t][cd][r];
            }
}

// Reduce chunk partials per (nh,qt), divide by rowsum, write output.
template<int CHUNK>
__global__ __launch_bounds__(256) void reduce_div_kernel(
    const float* __restrict__ O_part, const float* __restrict__ rs_part,
    float* __restrict__ out)
{
    const int idx = blockIdx.x * 256 + threadIdx.x;
    const int d4 = idx & 15;
    const int l  = (idx >> 4) & (L_SEQ - 1);
    const int nh = idx >> 15;
    const int qt = l >> 7;
    const int row = l & 127;
    int cs = 0;
    for (int q = 0; q < qt; ++q) cs += (2*q + 2 + CHUNK - 1) / CHUNK;
    const int nch = (2*qt + 2 + CHUNK - 1) / CHUNK;

    float4 o = {0.f, 0.f, 0.f, 0.f};
    float rssum = 0.f;
    for (int ci = 0; ci < nch; ++ci) {
        const size_t slab = (size_t)(cs + ci) * 16 + nh;
        const float4 p = *(const float4*)(O_part + slab*8192 + row*64 + d4*4);
        o.x += p.x; o.y += p.y; o.z += p.z; o.w += p.w;
        rssum += rs_part[slab*128 + row];
    }
    const float inv = 1.0f / rssum;
    float4 r;
    r.x = o.x * inv; r.y = o.y * inv; r.z = o.z * inv; r.w = o.w * inv;
    const int n = nh >> 3, h = nh & 7;
    *(float4*)(out + ((size_t)(n*L_SEQ + l))*DMODEL + h*DHEAD + d4*4) = r;
}

extern "C" void kernel_launch(void* const* d_in, const int* in_sizes, int n_in,
                              void* d_out, int out_size, void* d_ws, size_t ws_size,
                              hipStream_t stream) {
    const float* y         = (const float*)d_in[0];
    const float* positions = (const float*)d_in[1];
    const float* Wq        = (const float*)d_in[2];
    const float* Wk        = (const float*)d_in[3];
    const float* Wv        = (const float*)d_in[4];
    const float* coeff     = (const float*)d_in[5];
    const float* pw        = (const float*)d_in[6];
    const float* pb        = (const float*)d_in[7];
    float* out = (float*)d_out;

    const size_t SQK = (size_t)16 * QK_STRIDE;   // shorts (8 MB)
    const size_t SV  = (size_t)16 * V_STRIDE;    // shorts (4 MB)
    const size_t SY  = (size_t)4096 * 512;       // 2M shorts (4 MB)
    const size_t SW  = (size_t)3 * 512 * 512;    // 768K shorts (1.5 MB)
    short* Qh = (short*)d_ws;
    short* Ql = Qh + SQK;
    short* Kh = Ql + SQK;
    short* Kl = Kh + SQK;
    short* Vh = Kl + SQK;
    short* Vl = Vh + SV;
    short* yh = Vl + SV;
    short* yl = yh + SY;
    short* wh = yl + SY;
    short* wl = wh + SW;
    float* O_part = (float*)(wl + SW);
    const size_t base_bytes = (SQK*4 + SV*2 + SY*2 + SW*2) * sizeof(short);
    const size_t per_slot   = (size_t)16 * (8192 + 128) * sizeof(float);

    split_kernel<<<dim3(1408), dim3(256), 0, stream>>>(y, Wq, Wk, Wv, yh, yl, wh, wl);
    prep_kernel<<<dim3(32, 8, 3), dim3(256), 0, stream>>>(
        yh, yl, wh, wl, positions, coeff, pw, pb, Qh, Ql, Kh, Kl, Vh, Vl);

    if (ws_size >= base_bytes + 136 * per_slot) {
        float* rs_part = O_part + (size_t)136 * 16 * 8192;
        attn_kernel<2><<<dim3(136, 16), dim3(256), 0, stream>>>(
            Qh, Ql, Kh, Kl, Vh, Vl, O_part, rs_part);
        reduce_div_kernel<2><<<dim3(2048), dim3(256), 0, stream>>>(O_part, rs_part, out);
    } else if (ws_size >= base_bytes + 72 * per_slot) {
        float* rs_part = O_part + (size_t)72 * 16 * 8192;
        attn_kernel<4><<<dim3(72, 16), dim3(256), 0, stream>>>(
            Qh, Ql, Kh, Kl, Vh, Vl, O_part, rs_part);
        reduce_div_kernel<4><<<dim3(2048), dim3(256), 0, stream>>>(O_part, rs_part, out);
    } else {
        float* rs_part = O_part + (size_t)40 * 16 * 8192;
        attn_kernel<8><<<dim3(40, 16), dim3(256), 0, stream>>>(
            Qh, Ql, Kh, Kl, Vh, Vl, O_part, rs_part);
        reduce_div_kernel<8><<<dim3(2048), dim3(256), 0, stream>>>(O_part, rs_part, out);
    }
}

// Round 11
// 113.451 us; speedup vs baseline: 2.3916x; 1.1006x over previous
//
#include <hip/hip_runtime.h>
#include <hip/hip_bf16.h>

typedef __attribute__((ext_vector_type(8))) short bf16x8;
typedef __attribute__((ext_vector_type(4))) float f32x4;
typedef unsigned int u32;

#define L_SEQ 2048
#define NHEAD 8
#define DHEAD 64
#define DMODEL 512
#define QK_STRIDE 262144          // per-nh shorts, frag-major Q/K (2048*128)
#define V_STRIDE  131072          // per-nh shorts, frag-major V (2048*64)

__device__ __forceinline__ short f2bf(float f) {
    union { float f; unsigned u; } x; x.f = f;
    unsigned r = x.u + 0x7FFFu + ((x.u >> 16) & 1u);
    return (short)(r >> 16);
}

__device__ __forceinline__ void split1(float x, short& hi, short& lo) {
    unsigned uh = __float_as_uint(x) & 0xFFFF0000u;
    hi = (short)(uh >> 16);
    lo = f2bf(x - __uint_as_float(uh));
}

__device__ __forceinline__ void split8(const float* p, bf16x8& hi, bf16x8& lo) {
    #pragma unroll
    for (int i = 0; i < 8; ++i) {
        float x = p[i];
        unsigned uh = __float_as_uint(x) & 0xFFFF0000u;
        hi[i] = (short)(uh >> 16);
        lo[i] = f2bf(x - __uint_as_float(uh));
    }
}

__device__ __forceinline__ u32 cvtpk_bf16(float a, float b) {
    u32 r;
    asm("v_cvt_pk_bf16_f32 %0, %1, %2" : "=v"(r) : "v"(a), "v"(b));
    return r;
}

// async global->LDS, 16B per lane, wave-uniform LDS base (HW adds lane*16)
__device__ __forceinline__ void gload_lds16(const void* g, void* l) {
    __builtin_amdgcn_global_load_lds(
        (const __attribute__((address_space(1))) unsigned int*)g,
        (__attribute__((address_space(3))) unsigned int*)l, 16, 0, 0);
}

// ---------------------------------------------------------------------------
// Kernel 0: one-time split of y / W into frag-major bf16 hi/lo arrays.
// ---------------------------------------------------------------------------
__global__ __launch_bounds__(256) void split_kernel(
    const float* __restrict__ y,
    const float* __restrict__ Wq, const float* __restrict__ Wk, const float* __restrict__ Wv,
    short* __restrict__ yh, short* __restrict__ yl,
    short* __restrict__ wh, short* __restrict__ wl)
{
    const int wv = threadIdx.x >> 6, ln = threadIdx.x & 63;
    const int u = blockIdx.x * 4 + wv;          // 0..5631
    float tmp[8];
    if (u < 4096) {
        const int B = u >> 4, kb = u & 15;
        const int row = B*16 + (ln & 15);
        const int k   = kb*32 + (ln >> 4)*8;
        const float* src = y + (size_t)row * DMODEL + k;
        *(float4*)tmp       = *(const float4*)src;
        *(float4*)(tmp + 4) = *(const float4*)(src + 4);
        bf16x8 hi, lo;
        split8(tmp, hi, lo);
        const size_t dst = (size_t)u*512 + ln*8;
        *(bf16x8*)(yh + dst) = hi;
        *(bf16x8*)(yl + dst) = lo;
    } else {
        const int u2 = u - 4096;                // 0..1535
        const int mat = u2 >> 9;
        const int r   = u2 & 511;
        const int C = r >> 4, kb = r & 15;
        const float* W = (mat == 0) ? Wq : (mat == 1) ? Wk : Wv;
        const int col = C*16 + (ln & 15);
        const int k   = kb*32 + (ln >> 4)*8;
        const float* src = W + (size_t)col * DMODEL + k;
        *(float4*)tmp       = *(const float4*)src;
        *(float4*)(tmp + 4) = *(const float4*)(src + 4);
        bf16x8 hi, lo;
        split8(tmp, hi, lo);
        const size_t dst = (size_t)u2*512 + ln*8;
        *(bf16x8*)(wh + dst) = hi;
        *(bf16x8*)(wl + dst) = lo;
    }
}

// ---------------------------------------------------------------------------
// Kernel 1: C = y @ W^T, pure bf16 3-term MFMA from pre-split frag-major
// arrays. Epilogues write FRAG-MAJOR layouts for attn. Grid (32, 8, 3).
// ---------------------------------------------------------------------------
__global__ __launch_bounds__(256) void prep_kernel(
    const short* __restrict__ yh, const short* __restrict__ yl,
    const short* __restrict__ wh, const short* __restrict__ wl,
    const float* __restrict__ positions,
    const float* __restrict__ coeff, const float* __restrict__ pw, const float* __restrict__ pb,
    short* __restrict__ Qh, short* __restrict__ Ql,
    short* __restrict__ Kh, short* __restrict__ Kl,
    short* __restrict__ Vh, short* __restrict__ Vl)
{
    __shared__ float vtile[128][65];
    const int mode = blockIdx.z;
    const int m_base = blockIdx.x * 128;
    const int h = blockIdx.y;
    const int n_base = h * 64;
    const int tid = threadIdx.x;
    const int lane = tid & 63;
    const int wv = tid >> 6;
    const int lr = lane & 15;
    const int lg = lane >> 4;

    const short* whm = wh + (size_t)mode * 262144;
    const short* wlm = wl + (size_t)mode * 262144;
    const int Ba0 = blockIdx.x*8 + wv*2;

    f32x4 acc[2][4];
    #pragma unroll
    for (int t = 0; t < 2; ++t)
        #pragma unroll
        for (int c = 0; c < 4; ++c) acc[t][c] = (f32x4){0.f, 0.f, 0.f, 0.f};

    #pragma unroll 4
    for (int kb = 0; kb < 16; ++kb) {
        bf16x8 ah[2], al[2], bh[4], bl[4];
        #pragma unroll
        for (int t = 0; t < 2; ++t) {
            const size_t off = ((size_t)((Ba0 + t)*16 + kb)*64 + lane)*8;
            ah[t] = *(const bf16x8*)(yh + off);
            al[t] = *(const bf16x8*)(yl + off);
        }
        #pragma unroll
        for (int c = 0; c < 4; ++c) {
            const size_t off = ((size_t)((h*4 + c)*16 + kb)*64 + lane)*8;
            bh[c] = *(const bf16x8*)(whm + off);
            bl[c] = *(const bf16x8*)(wlm + off);
        }
        #pragma unroll
        for (int t = 0; t < 2; ++t)
            #pragma unroll
            for (int c = 0; c < 4; ++c) {
                acc[t][c] = __builtin_amdgcn_mfma_f32_16x16x32_bf16(ah[t], bh[c], acc[t][c], 0, 0, 0);
                acc[t][c] = __builtin_amdgcn_mfma_f32_16x16x32_bf16(ah[t], bl[c], acc[t][c], 0, 0, 0);
                acc[t][c] = __builtin_amdgcn_mfma_f32_16x16x32_bf16(al[t], bh[c], acc[t][c], 0, 0, 0);
            }
    }

    const int n_idx = m_base >> 11;
    const int nh = n_idx * NHEAD + h;

    if (mode == 2) {
        #pragma unroll
        for (int t = 0; t < 2; ++t)
            #pragma unroll
            for (int c = 0; c < 4; ++c)
                #pragma unroll
                for (int r = 0; r < 4; ++r)
                    vtile[wv*32 + t*16 + lg*4 + r][c*16 + lr] = acc[t][c][r];
        __syncthreads();
        const size_t vbase = (size_t)nh * V_STRIDE;
        #pragma unroll
        for (int i = 0; i < 32; ++i) {
            const int key_l = (tid & 7) + 8*(i & 15);          // 0..127
            const int d     = (tid >> 3) + 32*(i >> 4);        // 0..63
            const int key   = (m_base & (L_SEQ - 1)) + key_l;
            short th, tl;
            split1(vtile[key_l][d], th, tl);
            const size_t idx = vbase +
                ((size_t)((key >> 5)*4 + (d >> 4))*64 + (d & 15) + 16*((key >> 3) & 3))*8 + (key & 7);
            Vh[idx] = th; Vl[idx] = tl;
        }
    } else {
        short* OUTh = (mode == 0) ? Qh : Kh;
        short* OUTl = (mode == 0) ? Ql : Kl;
        const size_t qbase_nh = (size_t)nh * QK_STRIDE;
        #pragma unroll
        for (int t = 0; t < 2; ++t) {
            #pragma unroll
            for (int c = 0; c < 4; ++c) {
                const int d = c*16 + lr;
                const float pwv = pw[n_base + d];
                const float pbv = pb[n_base + d];
                const float cf  = (mode == 0) ? coeff[n_base + d] : 1.0f;
                const int lane_t = 16*((2*c + (lr >> 3)) & 3);
                const int j = lr & 7;
                #pragma unroll
                for (int r = 0; r < 4; ++r) {
                    const int gm = m_base + wv*32 + t*16 + lg*4 + r;
                    const int l = gm & (L_SEQ - 1);
                    const int B = l >> 4;
                    const float posv = positions[gm];
                    const float x = acc[t][c][r];
                    const float sp = fmaxf(x, 0.f) + __logf(1.f + __expf(-fabsf(x)));
                    const float p = pwv * posv + pbv;
                    const float cs = __cosf(p), sn = __sinf(p);
                    short h1, l1, h2, l2;
                    split1(sp * cf * cs, h1, l1);
                    split1(sp * cf * sn, h2, l2);
                    const int ln = (l & 15) + lane_t;
                    const size_t idx_c = qbase_nh + ((size_t)(B*4 + (c >> 1))*64 + ln)*8 + j;
                    const size_t idx_s = qbase_nh + ((size_t)(B*4 + 2 + (c >> 1))*64 + ln)*8 + j;
                    OUTh[idx_c] = h1; OUTl[idx_c] = l1;
                    OUTh[idx_s] = h2; OUTl[idx_s] = l2;
                }
            }
        }
    }
}

// ---------------------------------------------------------------------------
// Kernel 2: split-K causal attention, LDS-staged K/V (R9 structure).
// R11: XCD-aware 1D grid decode — id&7 selects XCD (dispatch round-robin),
// each XCD owns 2 heads: per-XCD hot set 2*(1.5 K/V + 1 Q) = 5MB ~ L2-resident
// (R10: FETCH 129MB of 209MB staged = L2 thrash across all 16 heads).
// nh = (id&7)*2 + ((id>>3)&1), slot = id>>4.
// ---------------------------------------------------------------------------
template<int CHUNK>
__global__ __launch_bounds__(256) void attn_kernel(
    const short* __restrict__ Qh, const short* __restrict__ Ql,
    const short* __restrict__ Kh, const short* __restrict__ Kl,
    const short* __restrict__ Vh, const short* __restrict__ Vl,
    float* __restrict__ O_part, float* __restrict__ rs_part)
{
    __shared__ char s_lds[49152];
    const int id = blockIdx.x;
    const int nh   = (id & 7)*2 + ((id >> 3) & 1);
    const int slot = id >> 4;

    int rem = slot, qt = 0;
    for (qt = 0; qt < 16; ++qt) {
        const int nch = (2*qt + 2 + CHUNK - 1) / CHUNK;
        if (rem < nch) break;
        rem -= nch;
    }
    const int nst = 2*qt + 2;
    const int kt0 = rem * CHUNK;
    const int kt1 = (kt0 + CHUNK < nst) ? (kt0 + CHUNK) : nst;

    const int q_base = qt * 128;
    const int tid = threadIdx.x;
    const int lane = tid & 63;
    const int wv = tid >> 6;
    const int lr = lane & 15;
    const int lg = lane >> 4;

    const short* Qh_b = Qh + (size_t)nh * QK_STRIDE;
    const short* Ql_b = Ql + (size_t)nh * QK_STRIDE;
    const short* Kh_b = Kh + (size_t)nh * QK_STRIDE;
    const short* Kl_b = Kl + (size_t)nh * QK_STRIDE;
    const short* Vh_b = Vh + (size_t)nh * V_STRIDE;
    const short* Vl_b = Vl + (size_t)nh * V_STRIDE;

    bf16x8 qh[2][4], ql[2][4];
    #pragma unroll
    for (int t = 0; t < 2; ++t) {
        const int Bq = qt*8 + wv*2 + t;
        #pragma unroll
        for (int kh = 0; kh < 4; ++kh) {
            const size_t off = ((size_t)(Bq*4 + kh)*64 + lane)*8;
            qh[t][kh] = *(const bf16x8*)(Qh_b + off);
            ql[t][kh] = *(const bf16x8*)(Ql_b + off);
        }
    }

    f32x4 o_acc[2][4];
    float rs[2];
    #pragma unroll
    for (int t = 0; t < 2; ++t) {
        #pragma unroll
        for (int c = 0; c < 4; ++c) o_acc[t][c] = (f32x4){0.f, 0.f, 0.f, 0.f};
        rs[t] = 0.f;
    }

    const int addr0 = (lr + ((lg & 1) * 2) * 16) << 2;
    const int addr1 = addr0 + 64;
    const bool selhi = (lg >= 2);
    const int lb = lane << 4;

    for (int kt = kt0; kt < kt1; ++kt) {
        {
            const char* kh_src = (const char*)(Kh_b + (size_t)kt*8192);
            const char* kl_src = (const char*)(Kl_b + (size_t)kt*8192);
            const char* vh_src = (const char*)(Vh_b + (size_t)kt*4096);
            const char* vl_src = (const char*)(Vl_b + (size_t)kt*4096);
            #pragma unroll
            for (int i = 0; i < 12; ++i) {
                const int ch = wv*12 + i;
                const char* src;
                if (ch < 16)      src = kh_src + ch*1024;
                else if (ch < 32) src = kl_src + (ch-16)*1024;
                else if (ch < 40) src = vh_src + (ch-32)*1024;
                else              src = vl_src + (ch-40)*1024;
                gload_lds16(src + lb, s_lds + ch*1024);
            }
        }
        __syncthreads();

        f32x4 st[2][4];
        #pragma unroll
        for (int t = 0; t < 2; ++t)
            #pragma unroll
            for (int c = 0; c < 4; ++c) st[t][c] = (f32x4){0.f, 0.f, 0.f, 0.f};

        #pragma unroll
        for (int c = 0; c < 4; ++c) {
            #pragma unroll
            for (int kh = 0; kh < 4; ++kh) {
                const int boff = (c*4 + kh)*1024 + lb;
                const bf16x8 kfh = *(const bf16x8*)(s_lds + boff);
                const bf16x8 kfl = *(const bf16x8*)(s_lds + 16384 + boff);
                #pragma unroll
                for (int t = 0; t < 2; ++t) {
                    st[t][c] = __builtin_amdgcn_mfma_f32_16x16x32_bf16(kfh, qh[t][kh], st[t][c], 0, 0, 0);
                    st[t][c] = __builtin_amdgcn_mfma_f32_16x16x32_bf16(kfh, ql[t][kh], st[t][c], 0, 0, 0);
                    st[t][c] = __builtin_amdgcn_mfma_f32_16x16x32_bf16(kfl, qh[t][kh], st[t][c], 0, 0, 0);
                }
            }
        }

        const int k0 = kt * 64;
        const bool domask = (kt >= 2*qt);
        #pragma unroll
        for (int t = 0; t < 2; ++t) {
            const int gq = q_base + wv*32 + t*16 + lr;
            float part = 0.f;
            #pragma unroll
            for (int c = 0; c < 4; ++c)
                #pragma unroll
                for (int r = 0; r < 4; ++r) {
                    const int gk = k0 + c*16 + lg*4 + r;
                    float v = st[t][c][r];
                    if (domask && gk > gq) v = 0.f;
                    st[t][c][r] = v;
                    part += v;
                }
            part += __shfl_xor(part, 16);
            part += __shfl_xor(part, 32);
            rs[t] += part;
        }

        u32 pwh[2][4][2], pwl[2][4][2];
        #pragma unroll
        for (int t = 0; t < 2; ++t)
            #pragma unroll
            for (int c = 0; c < 4; ++c) {
                const u32 b0 = __float_as_uint(st[t][c][0]);
                const u32 b1 = __float_as_uint(st[t][c][1]);
                const u32 b2 = __float_as_uint(st[t][c][2]);
                const u32 b3 = __float_as_uint(st[t][c][3]);
                pwh[t][c][0] = (b1 & 0xFFFF0000u) | (b0 >> 16);
                pwh[t][c][1] = (b3 & 0xFFFF0000u) | (b2 >> 16);
                const float l0 = st[t][c][0] - __uint_as_float(b0 & 0xFFFF0000u);
                const float l1 = st[t][c][1] - __uint_as_float(b1 & 0xFFFF0000u);
                const float l2 = st[t][c][2] - __uint_as_float(b2 & 0xFFFF0000u);
                const float l3 = st[t][c][3] - __uint_as_float(b3 & 0xFFFF0000u);
                pwl[t][c][0] = cvtpk_bf16(l0, l1);
                pwl[t][c][1] = cvtpk_bf16(l2, l3);
            }

        #pragma unroll
        for (int kc = 0; kc < 2; ++kc) {
            union { u32 u[4]; bf16x8 v; } pah[2], pal[2];
            #pragma unroll
            for (int t = 0; t < 2; ++t) {
                u32 a, b;
                a = (u32)__builtin_amdgcn_ds_bpermute(addr0, (int)pwh[t][2*kc][0]);
                b = (u32)__builtin_amdgcn_ds_bpermute(addr0, (int)pwh[t][2*kc+1][0]);
                pah[t].u[0] = selhi ? b : a;
                a = (u32)__builtin_amdgcn_ds_bpermute(addr0, (int)pwh[t][2*kc][1]);
                b = (u32)__builtin_amdgcn_ds_bpermute(addr0, (int)pwh[t][2*kc+1][1]);
                pah[t].u[1] = selhi ? b : a;
                a = (u32)__builtin_amdgcn_ds_bpermute(addr1, (int)pwh[t][2*kc][0]);
                b = (u32)__builtin_amdgcn_ds_bpermute(addr1, (int)pwh[t][2*kc+1][0]);
                pah[t].u[2] = selhi ? b : a;
                a = (u32)__builtin_amdgcn_ds_bpermute(addr1, (int)pwh[t][2*kc][1]);
                b = (u32)__builtin_amdgcn_ds_bpermute(addr1, (int)pwh[t][2*kc+1][1]);
                pah[t].u[3] = selhi ? b : a;

                a = (u32)__builtin_amdgcn_ds_bpermute(addr0, (int)pwl[t][2*kc][0]);
                b = (u32)__builtin_amdgcn_ds_bpermute(addr0, (int)pwl[t][2*kc+1][0]);
                pal[t].u[0] = selhi ? b : a;
                a = (u32)__builtin_amdgcn_ds_bpermute(addr0, (int)pwl[t][2*kc][1]);
                b = (u32)__builtin_amdgcn_ds_bpermute(addr0, (int)pwl[t][2*kc+1][1]);
                pal[t].u[1] = selhi ? b : a;
                a = (u32)__builtin_amdgcn_ds_bpermute(addr1, (int)pwl[t][2*kc][0]);
                b = (u32)__builtin_amdgcn_ds_bpermute(addr1, (int)pwl[t][2*kc+1][0]);
                pal[t].u[2] = selhi ? b : a;
                a = (u32)__builtin_amdgcn_ds_bpermute(addr1, (int)pwl[t][2*kc][1]);
                b = (u32)__builtin_amdgcn_ds_bpermute(addr1, (int)pwl[t][2*kc+1][1]);
                pal[t].u[3] = selhi ? b : a;
            }
            #pragma unroll
            for (int cd = 0; cd < 4; ++cd) {
                const int voff = (kc*4 + cd)*1024 + lb;
                const bf16x8 vfh = *(const bf16x8*)(s_lds + 32768 + voff);
                const bf16x8 vfl = *(const bf16x8*)(s_lds + 40960 + voff);
                #pragma unroll
                for (int t = 0; t < 2; ++t) {
                    o_acc[t][cd] = __builtin_amdgcn_mfma_f32_16x16x32_bf16(pah[t].v, vfh, o_acc[t][cd], 0, 0, 0);
                    o_acc[t][cd] = __builtin_amdgcn_mfma_f32_16x16x32_bf16(pah[t].v, vfl, o_acc[t][cd], 0, 0, 0);
                    o_acc[t][cd] = __builtin_amdgcn_mfma_f32_16x16x32_bf16(pal[t].v, vfh, o_acc[t][cd], 0, 0, 0);
                }
            }
        }
        __syncthreads();
    }

    const size_t slab = (size_t)slot * 16 + nh;
    #pragma unroll
    for (int t = 0; t < 2; ++t)
        if (lg == 0)
            rs_part[slab*128 + wv*32 + t*16 + lr] = rs[t];

    #pragma unroll
    for (int t = 0; t < 2; ++t)
        #pragma unroll
        for (int cd = 0; cd < 4; ++cd)
            #pragma unroll
            for (int r = 0; r < 4; ++r) {
                const int row = wv*32 + t*16 + lg*4 + r;
                O_part[slab*8192 + row*64 + cd*16 + lr] = o_acc[t][cd][r];
            }
}

// Reduce chunk partials per (nh,qt), divide by rowsum, write output.
template<int CHUNK>
__global__ __launch_bounds__(256) void reduce_div_kernel(
    const float* __restrict__ O_part, const float* __restrict__ rs_part,
    float* __restrict__ out)
{
    const int idx = blockIdx.x * 256 + threadIdx.x;
    const int d4 = idx & 15;
    const int l  = (idx >> 4) & (L_SEQ - 1);
    const int nh = idx >> 15;
    const int qt = l >> 7;
    const int row = l & 127;
    int cs = 0;
    for (int q = 0; q < qt; ++q) cs += (2*q + 2 + CHUNK - 1) / CHUNK;
    const int nch = (2*qt + 2 + CHUNK - 1) / CHUNK;

    float4 o = {0.f, 0.f, 0.f, 0.f};
    float rssum = 0.f;
    for (int ci = 0; ci < nch; ++ci) {
        const size_t slab = (size_t)(cs + ci) * 16 + nh;
        const float4 p = *(const float4*)(O_part + slab*8192 + row*64 + d4*4);
        o.x += p.x; o.y += p.y; o.z += p.z; o.w += p.w;
        rssum += rs_part[slab*128 + row];
    }
    const float inv = 1.0f / rssum;
    float4 r;
    r.x = o.x * inv; r.y = o.y * inv; r.z = o.z * inv; r.w = o.w * inv;
    const int n = nh >> 3, h = nh & 7;
    *(float4*)(out + ((size_t)(n*L_SEQ + l))*DMODEL + h*DHEAD + d4*4) = r;
}

extern "C" void kernel_launch(void* const* d_in, const int* in_sizes, int n_in,
                              void* d_out, int out_size, void* d_ws, size_t ws_size,
                              hipStream_t stream) {
    const float* y         = (const float*)d_in[0];
    const float* positions = (const float*)d_in[1];
    const float* Wq        = (const float*)d_in[2];
    const float* Wk        = (const float*)d_in[3];
    const float* Wv        = (const float*)d_in[4];
    const float* coeff     = (const float*)d_in[5];
    const float* pw        = (const float*)d_in[6];
    const float* pb        = (const float*)d_in[7];
    float* out = (float*)d_out;

    const size_t SQK = (size_t)16 * QK_STRIDE;   // shorts (8 MB)
    const size_t SV  = (size_t)16 * V_STRIDE;    // shorts (4 MB)
    const size_t SY  = (size_t)4096 * 512;       // 2M shorts (4 MB)
    const size_t SW  = (size_t)3 * 512 * 512;    // 768K shorts (1.5 MB)
    short* Qh = (short*)d_ws;
    short* Ql = Qh + SQK;
    short* Kh = Ql + SQK;
    short* Kl = Kh + SQK;
    short* Vh = Kl + SQK;
    short* Vl = Vh + SV;
    short* yh = Vl + SV;
    short* yl = yh + SY;
    short* wh = yl + SY;
    short* wl = wh + SW;
    float* O_part = (float*)(wl + SW);
    const size_t base_bytes = (SQK*4 + SV*2 + SY*2 + SW*2) * sizeof(short);
    const size_t per_slot   = (size_t)16 * (8192 + 128) * sizeof(float);

    split_kernel<<<dim3(1408), dim3(256), 0, stream>>>(y, Wq, Wk, Wv, yh, yl, wh, wl);
    prep_kernel<<<dim3(32, 8, 3), dim3(256), 0, stream>>>(
        yh, yl, wh, wl, positions, coeff, pw, pb, Qh, Ql, Kh, Kl, Vh, Vl);

    if (ws_size >= base_bytes + 136 * per_slot) {
        float* rs_part = O_part + (size_t)136 * 16 * 8192;
        attn_kernel<2><<<dim3(136 * 16), dim3(256), 0, stream>>>(
            Qh, Ql, Kh, Kl, Vh, Vl, O_part, rs_part);
        reduce_div_kernel<2><<<dim3(2048), dim3(256), 0, stream>>>(O_part, rs_part, out);
    } else if (ws_size >= base_bytes + 72 * per_slot) {
        float* rs_part = O_part + (size_t)72 * 16 * 8192;
        attn_kernel<4><<<dim3(72 * 16), dim3(256), 0, stream>>>(
            Qh, Ql, Kh, Kl, Vh, Vl, O_part, rs_part);
        reduce_div_kernel<4><<<dim3(2048), dim3(256), 0, stream>>>(O_part, rs_part, out);
    } else {
        float* rs_part = O_part + (size_t)40 * 16 * 8192;
        attn_kernel<8><<<dim3(40 * 16), dim3(256), 0, stream>>>(
            Qh, Ql, Kh, Kl, Vh, Vl, O_part, rs_part);
        reduce_div_kernel<8><<<dim3(2048), dim3(256), 0, stream>>>(O_part, rs_part, out);
    }
}

// Round 12
// 101.547 us; speedup vs baseline: 2.6720x; 1.1172x over previous
//
#include <hip/hip_runtime.h>
#include <hip/hip_bf16.h>

typedef __attribute__((ext_vector_type(8))) short bf16x8;
typedef __attribute__((ext_vector_type(4))) float f32x4;
typedef unsigned int u32;

#define L_SEQ 2048
#define NHEAD 8
#define DHEAD 64
#define DMODEL 512
#define QK_STRIDE 262144          // per-nh shorts, frag-major Q/K (2048*128)
#define V_STRIDE  131072          // per-nh shorts, frag-major V (2048*64)

__device__ __forceinline__ short f2bf(float f) {
    union { float f; unsigned u; } x; x.f = f;
    unsigned r = x.u + 0x7FFFu + ((x.u >> 16) & 1u);
    return (short)(r >> 16);
}

__device__ __forceinline__ void split1(float x, short& hi, short& lo) {
    unsigned uh = __float_as_uint(x) & 0xFFFF0000u;
    hi = (short)(uh >> 16);
    lo = f2bf(x - __uint_as_float(uh));
}

__device__ __forceinline__ void split8(const float* p, bf16x8& hi, bf16x8& lo) {
    #pragma unroll
    for (int i = 0; i < 8; ++i) {
        float x = p[i];
        unsigned uh = __float_as_uint(x) & 0xFFFF0000u;
        hi[i] = (short)(uh >> 16);
        lo[i] = f2bf(x - __uint_as_float(uh));
    }
}

__device__ __forceinline__ u32 cvtpk_bf16(float a, float b) {
    u32 r;
    asm("v_cvt_pk_bf16_f32 %0, %1, %2" : "=v"(r) : "v"(a), "v"(b));
    return r;
}

// async global->LDS, 16B per lane, wave-uniform LDS base (HW adds lane*16)
__device__ __forceinline__ void gload_lds16(const void* g, void* l) {
    __builtin_amdgcn_global_load_lds(
        (const __attribute__((address_space(1))) unsigned int*)g,
        (__attribute__((address_space(3))) unsigned int*)l, 16, 0, 0);
}

// ---------------------------------------------------------------------------
// Kernel 0: one-time split of y / W into frag-major bf16 hi/lo arrays.
// ---------------------------------------------------------------------------
__global__ __launch_bounds__(256) void split_kernel(
    const float* __restrict__ y,
    const float* __restrict__ Wq, const float* __restrict__ Wk, const float* __restrict__ Wv,
    short* __restrict__ yh, short* __restrict__ yl,
    short* __restrict__ wh, short* __restrict__ wl)
{
    const int wv = threadIdx.x >> 6, ln = threadIdx.x & 63;
    const int u = blockIdx.x * 4 + wv;          // 0..5631
    float tmp[8];
    if (u < 4096) {
        const int B = u >> 4, kb = u & 15;
        const int row = B*16 + (ln & 15);
        const int k   = kb*32 + (ln >> 4)*8;
        const float* src = y + (size_t)row * DMODEL + k;
        *(float4*)tmp       = *(const float4*)src;
        *(float4*)(tmp + 4) = *(const float4*)(src + 4);
        bf16x8 hi, lo;
        split8(tmp, hi, lo);
        const size_t dst = (size_t)u*512 + ln*8;
        *(bf16x8*)(yh + dst) = hi;
        *(bf16x8*)(yl + dst) = lo;
    } else {
        const int u2 = u - 4096;                // 0..1535
        const int mat = u2 >> 9;
        const int r   = u2 & 511;
        const int C = r >> 4, kb = r & 15;
        const float* W = (mat == 0) ? Wq : (mat == 1) ? Wk : Wv;
        const int col = C*16 + (ln & 15);
        const int k   = kb*32 + (ln >> 4)*8;
        const float* src = W + (size_t)col * DMODEL + k;
        *(float4*)tmp       = *(const float4*)src;
        *(float4*)(tmp + 4) = *(const float4*)(src + 4);
        bf16x8 hi, lo;
        split8(tmp, hi, lo);
        const size_t dst = (size_t)u2*512 + ln*8;
        *(bf16x8*)(wh + dst) = hi;
        *(bf16x8*)(wl + dst) = lo;
    }
}

// ---------------------------------------------------------------------------
// Kernel 1: C = y @ W^T, pure bf16 3-term MFMA from pre-split frag-major
// arrays. Epilogues write FRAG-MAJOR layouts for attn. Grid (32, 8, 3).
// ---------------------------------------------------------------------------
__global__ __launch_bounds__(256) void prep_kernel(
    const short* __restrict__ yh, const short* __restrict__ yl,
    const short* __restrict__ wh, const short* __restrict__ wl,
    const float* __restrict__ positions,
    const float* __restrict__ coeff, const float* __restrict__ pw, const float* __restrict__ pb,
    short* __restrict__ Qh, short* __restrict__ Ql,
    short* __restrict__ Kh, short* __restrict__ Kl,
    short* __restrict__ Vh, short* __restrict__ Vl)
{
    __shared__ float vtile[128][65];
    const int mode = blockIdx.z;
    const int m_base = blockIdx.x * 128;
    const int h = blockIdx.y;
    const int n_base = h * 64;
    const int tid = threadIdx.x;
    const int lane = tid & 63;
    const int wv = tid >> 6;
    const int lr = lane & 15;
    const int lg = lane >> 4;

    const short* whm = wh + (size_t)mode * 262144;
    const short* wlm = wl + (size_t)mode * 262144;
    const int Ba0 = blockIdx.x*8 + wv*2;

    f32x4 acc[2][4];
    #pragma unroll
    for (int t = 0; t < 2; ++t)
        #pragma unroll
        for (int c = 0; c < 4; ++c) acc[t][c] = (f32x4){0.f, 0.f, 0.f, 0.f};

    #pragma unroll 4
    for (int kb = 0; kb < 16; ++kb) {
        bf16x8 ah[2], al[2], bh[4], bl[4];
        #pragma unroll
        for (int t = 0; t < 2; ++t) {
            const size_t off = ((size_t)((Ba0 + t)*16 + kb)*64 + lane)*8;
            ah[t] = *(const bf16x8*)(yh + off);
            al[t] = *(const bf16x8*)(yl + off);
        }
        #pragma unroll
        for (int c = 0; c < 4; ++c) {
            const size_t off = ((size_t)((h*4 + c)*16 + kb)*64 + lane)*8;
            bh[c] = *(const bf16x8*)(whm + off);
            bl[c] = *(const bf16x8*)(wlm + off);
        }
        #pragma unroll
        for (int t = 0; t < 2; ++t)
            #pragma unroll
            for (int c = 0; c < 4; ++c) {
                acc[t][c] = __builtin_amdgcn_mfma_f32_16x16x32_bf16(ah[t], bh[c], acc[t][c], 0, 0, 0);
                acc[t][c] = __builtin_amdgcn_mfma_f32_16x16x32_bf16(ah[t], bl[c], acc[t][c], 0, 0, 0);
                acc[t][c] = __builtin_amdgcn_mfma_f32_16x16x32_bf16(al[t], bh[c], acc[t][c], 0, 0, 0);
            }
    }

    const int n_idx = m_base >> 11;
    const int nh = n_idx * NHEAD + h;

    if (mode == 2) {
        #pragma unroll
        for (int t = 0; t < 2; ++t)
            #pragma unroll
            for (int c = 0; c < 4; ++c)
                #pragma unroll
                for (int r = 0; r < 4; ++r)
                    vtile[wv*32 + t*16 + lg*4 + r][c*16 + lr] = acc[t][c][r];
        __syncthreads();
        const size_t vbase = (size_t)nh * V_STRIDE;
        #pragma unroll
        for (int i = 0; i < 32; ++i) {
            const int key_l = (tid & 7) + 8*(i & 15);          // 0..127
            const int d     = (tid >> 3) + 32*(i >> 4);        // 0..63
            const int key   = (m_base & (L_SEQ - 1)) + key_l;
            short th, tl;
            split1(vtile[key_l][d], th, tl);
            const size_t idx = vbase +
                ((size_t)((key >> 5)*4 + (d >> 4))*64 + (d & 15) + 16*((key >> 3) & 3))*8 + (key & 7);
            Vh[idx] = th; Vl[idx] = tl;
        }
    } else {
        short* OUTh = (mode == 0) ? Qh : Kh;
        short* OUTl = (mode == 0) ? Ql : Kl;
        const size_t qbase_nh = (size_t)nh * QK_STRIDE;
        #pragma unroll
        for (int t = 0; t < 2; ++t) {
            #pragma unroll
            for (int c = 0; c < 4; ++c) {
                const int d = c*16 + lr;
                const float pwv = pw[n_base + d];
                const float pbv = pb[n_base + d];
                const float cf  = (mode == 0) ? coeff[n_base + d] : 1.0f;
                const int lane_t = 16*((2*c + (lr >> 3)) & 3);
                const int j = lr & 7;
                #pragma unroll
                for (int r = 0; r < 4; ++r) {
                    const int gm = m_base + wv*32 + t*16 + lg*4 + r;
                    const int l = gm & (L_SEQ - 1);
                    const int B = l >> 4;
                    const float posv = positions[gm];
                    const float x = acc[t][c][r];
                    const float sp = fmaxf(x, 0.f) + __logf(1.f + __expf(-fabsf(x)));
                    const float p = pwv * posv + pbv;
                    const float cs = __cosf(p), sn = __sinf(p);
                    short h1, l1, h2, l2;
                    split1(sp * cf * cs, h1, l1);
                    split1(sp * cf * sn, h2, l2);
                    const int ln = (l & 15) + lane_t;
                    const size_t idx_c = qbase_nh + ((size_t)(B*4 + (c >> 1))*64 + ln)*8 + j;
                    const size_t idx_s = qbase_nh + ((size_t)(B*4 + 2 + (c >> 1))*64 + ln)*8 + j;
                    OUTh[idx_c] = h1; OUTl[idx_c] = l1;
                    OUTh[idx_s] = h2; OUTl[idx_s] = l2;
                }
            }
        }
    }
}

// ---------------------------------------------------------------------------
// Kernel 2: split-K causal attention. R12: (a) K double-buffered in LDS
// (2x32KB), stage kt+1 while computing kt, ONE barrier per kstep — staging
// latency off the critical path; (b) V loads direct global->reg (L2-resident
// per-XCD), issued at iteration top, hidden under QK — LDS read traffic
// 192->128 KB per block-kstep (R11: LDS pipe was the dominant term).
// XCD-aware decode (R11). Swapped QK, bpermute PV, partial slabs.
// ---------------------------------------------------------------------------
template<int CHUNK>
__global__ __launch_bounds__(256) void attn_kernel(
    const short* __restrict__ Qh, const short* __restrict__ Ql,
    const short* __restrict__ Kh, const short* __restrict__ Kl,
    const short* __restrict__ Vh, const short* __restrict__ Vl,
    float* __restrict__ O_part, float* __restrict__ rs_part)
{
    __shared__ char s_lds[65536];   // 2 x (K-hi 16KB | K-lo 16KB)
    const int id = blockIdx.x;
    const int nh   = (id & 7)*2 + ((id >> 3) & 1);
    const int slot = id >> 4;

    int rem = slot, qt = 0;
    for (qt = 0; qt < 16; ++qt) {
        const int nch = (2*qt + 2 + CHUNK - 1) / CHUNK;
        if (rem < nch) break;
        rem -= nch;
    }
    const int nst = 2*qt + 2;
    const int kt0 = rem * CHUNK;
    const int kt1 = (kt0 + CHUNK < nst) ? (kt0 + CHUNK) : nst;

    const int q_base = qt * 128;
    const int tid = threadIdx.x;
    const int lane = tid & 63;
    const int wv = tid >> 6;
    const int lr = lane & 15;
    const int lg = lane >> 4;

    const short* Qh_b = Qh + (size_t)nh * QK_STRIDE;
    const short* Ql_b = Ql + (size_t)nh * QK_STRIDE;
    const short* Kh_b = Kh + (size_t)nh * QK_STRIDE;
    const short* Kl_b = Kl + (size_t)nh * QK_STRIDE;
    const short* Vh_b = Vh + (size_t)nh * V_STRIDE;
    const short* Vl_b = Vl + (size_t)nh * V_STRIDE;

    bf16x8 qh[2][4], ql[2][4];
    #pragma unroll
    for (int t = 0; t < 2; ++t) {
        const int Bq = qt*8 + wv*2 + t;
        #pragma unroll
        for (int kh = 0; kh < 4; ++kh) {
            const size_t off = ((size_t)(Bq*4 + kh)*64 + lane)*8;
            qh[t][kh] = *(const bf16x8*)(Qh_b + off);
            ql[t][kh] = *(const bf16x8*)(Ql_b + off);
        }
    }

    f32x4 o_acc[2][4];
    float rs[2];
    #pragma unroll
    for (int t = 0; t < 2; ++t) {
        #pragma unroll
        for (int c = 0; c < 4; ++c) o_acc[t][c] = (f32x4){0.f, 0.f, 0.f, 0.f};
        rs[t] = 0.f;
    }

    const int addr0 = (lr + ((lg & 1) * 2) * 16) << 2;
    const int addr1 = addr0 + 64;
    const bool selhi = (lg >= 2);
    const int lb = lane << 4;

    // prologue: stage K(kt0) into buffer 0
    {
        const char* kh_src = (const char*)(Kh_b + (size_t)kt0*8192);
        const char* kl_src = (const char*)(Kl_b + (size_t)kt0*8192);
        #pragma unroll
        for (int i = 0; i < 8; ++i) {
            const int ch = wv*8 + i;
            const char* src = (ch < 16) ? kh_src + ch*1024 : kl_src + (ch-16)*1024;
            gload_lds16(src + lb, s_lds + ch*1024);
        }
    }
    __syncthreads();

    int cur = 0;
    for (int kt = kt0; kt < kt1; ++kt) {
        // issue next-kstep K stage into the other buffer (hidden under compute)
        if (kt + 1 < kt1) {
            const char* kh_src = (const char*)(Kh_b + (size_t)(kt+1)*8192);
            const char* kl_src = (const char*)(Kl_b + (size_t)(kt+1)*8192);
            char* dst = s_lds + (cur ? 0 : 32768);
            #pragma unroll
            for (int i = 0; i < 8; ++i) {
                const int ch = wv*8 + i;
                const char* src = (ch < 16) ? kh_src + ch*1024 : kl_src + (ch-16)*1024;
                gload_lds16(src + lb, dst + ch*1024);
            }
        }

        // V frag loads for this kstep (global, L2-resident; hidden under QK)
        bf16x8 vfh[2][4], vfl[2][4];
        #pragma unroll
        for (int kc = 0; kc < 2; ++kc)
            #pragma unroll
            for (int cd = 0; cd < 4; ++cd) {
                const size_t voff = ((size_t)((kt*2 + kc)*4 + cd)*64 + lane)*8;
                vfh[kc][cd] = *(const bf16x8*)(Vh_b + voff);
                vfl[kc][cd] = *(const bf16x8*)(Vl_b + voff);
            }

        // ---- QK^T (swapped) from LDS buffer cur ----
        const char* kbuf = s_lds + (cur ? 32768 : 0);
        f32x4 st[2][4];
        #pragma unroll
        for (int t = 0; t < 2; ++t)
            #pragma unroll
            for (int c = 0; c < 4; ++c) st[t][c] = (f32x4){0.f, 0.f, 0.f, 0.f};

        #pragma unroll
        for (int c = 0; c < 4; ++c) {
            #pragma unroll
            for (int kh = 0; kh < 4; ++kh) {
                const int boff = (c*4 + kh)*1024 + lb;
                const bf16x8 kfh = *(const bf16x8*)(kbuf + boff);
                const bf16x8 kfl = *(const bf16x8*)(kbuf + 16384 + boff);
                #pragma unroll
                for (int t = 0; t < 2; ++t) {
                    st[t][c] = __builtin_amdgcn_mfma_f32_16x16x32_bf16(kfh, qh[t][kh], st[t][c], 0, 0, 0);
                    st[t][c] = __builtin_amdgcn_mfma_f32_16x16x32_bf16(kfh, ql[t][kh], st[t][c], 0, 0, 0);
                    st[t][c] = __builtin_amdgcn_mfma_f32_16x16x32_bf16(kfl, qh[t][kh], st[t][c], 0, 0, 0);
                }
            }
        }

        // ---- mask + rowsum ----
        const int k0 = kt * 64;
        const bool domask = (kt >= 2*qt);
        #pragma unroll
        for (int t = 0; t < 2; ++t) {
            const int gq = q_base + wv*32 + t*16 + lr;
            float part = 0.f;
            #pragma unroll
            for (int c = 0; c < 4; ++c)
                #pragma unroll
                for (int r = 0; r < 4; ++r) {
                    const int gk = k0 + c*16 + lg*4 + r;
                    float v = st[t][c][r];
                    if (domask && gk > gq) v = 0.f;
                    st[t][c][r] = v;
                    part += v;
                }
            part += __shfl_xor(part, 16);
            part += __shfl_xor(part, 32);
            rs[t] += part;
        }

        // ---- pack S^T to bf16 hi/lo words ----
        u32 pwh[2][4][2], pwl[2][4][2];
        #pragma unroll
        for (int t = 0; t < 2; ++t)
            #pragma unroll
            for (int c = 0; c < 4; ++c) {
                const u32 b0 = __float_as_uint(st[t][c][0]);
                const u32 b1 = __float_as_uint(st[t][c][1]);
                const u32 b2 = __float_as_uint(st[t][c][2]);
                const u32 b3 = __float_as_uint(st[t][c][3]);
                pwh[t][c][0] = (b1 & 0xFFFF0000u) | (b0 >> 16);
                pwh[t][c][1] = (b3 & 0xFFFF0000u) | (b2 >> 16);
                const float l0 = st[t][c][0] - __uint_as_float(b0 & 0xFFFF0000u);
                const float l1 = st[t][c][1] - __uint_as_float(b1 & 0xFFFF0000u);
                const float l2 = st[t][c][2] - __uint_as_float(b2 & 0xFFFF0000u);
                const float l3 = st[t][c][3] - __uint_as_float(b3 & 0xFFFF0000u);
                pwl[t][c][0] = cvtpk_bf16(l0, l1);
                pwl[t][c][1] = cvtpk_bf16(l2, l3);
            }

        // ---- PV: gather PA frags via bpermute, V from registers ----
        #pragma unroll
        for (int kc = 0; kc < 2; ++kc) {
            union { u32 u[4]; bf16x8 v; } pah[2], pal[2];
            #pragma unroll
            for (int t = 0; t < 2; ++t) {
                u32 a, b;
                a = (u32)__builtin_amdgcn_ds_bpermute(addr0, (int)pwh[t][2*kc][0]);
                b = (u32)__builtin_amdgcn_ds_bpermute(addr0, (int)pwh[t][2*kc+1][0]);
                pah[t].u[0] = selhi ? b : a;
                a = (u32)__builtin_amdgcn_ds_bpermute(addr0, (int)pwh[t][2*kc][1]);
                b = (u32)__builtin_amdgcn_ds_bpermute(addr0, (int)pwh[t][2*kc+1][1]);
                pah[t].u[1] = selhi ? b : a;
                a = (u32)__builtin_amdgcn_ds_bpermute(addr1, (int)pwh[t][2*kc][0]);
                b = (u32)__builtin_amdgcn_ds_bpermute(addr1, (int)pwh[t][2*kc+1][0]);
                pah[t].u[2] = selhi ? b : a;
                a = (u32)__builtin_amdgcn_ds_bpermute(addr1, (int)pwh[t][2*kc][1]);
                b = (u32)__builtin_amdgcn_ds_bpermute(addr1, (int)pwh[t][2*kc+1][1]);
                pah[t].u[3] = selhi ? b : a;

                a = (u32)__builtin_amdgcn_ds_bpermute(addr0, (int)pwl[t][2*kc][0]);
                b = (u32)__builtin_amdgcn_ds_bpermute(addr0, (int)pwl[t][2*kc+1][0]);
                pal[t].u[0] = selhi ? b : a;
                a = (u32)__builtin_amdgcn_ds_bpermute(addr0, (int)pwl[t][2*kc][1]);
                b = (u32)__builtin_amdgcn_ds_bpermute(addr0, (int)pwl[t][2*kc+1][1]);
                pal[t].u[1] = selhi ? b : a;
                a = (u32)__builtin_amdgcn_ds_bpermute(addr1, (int)pwl[t][2*kc][0]);
                b = (u32)__builtin_amdgcn_ds_bpermute(addr1, (int)pwl[t][2*kc+1][0]);
                pal[t].u[2] = selhi ? b : a;
                a = (u32)__builtin_amdgcn_ds_bpermute(addr1, (int)pwl[t][2*kc][1]);
                b = (u32)__builtin_amdgcn_ds_bpermute(addr1, (int)pwl[t][2*kc+1][1]);
                pal[t].u[3] = selhi ? b : a;
            }
            #pragma unroll
            for (int cd = 0; cd < 4; ++cd) {
                #pragma unroll
                for (int t = 0; t < 2; ++t) {
                    o_acc[t][cd] = __builtin_amdgcn_mfma_f32_16x16x32_bf16(pah[t].v, vfh[kc][cd], o_acc[t][cd], 0, 0, 0);
                    o_acc[t][cd] = __builtin_amdgcn_mfma_f32_16x16x32_bf16(pah[t].v, vfl[kc][cd], o_acc[t][cd], 0, 0, 0);
                    o_acc[t][cd] = __builtin_amdgcn_mfma_f32_16x16x32_bf16(pal[t].v, vfh[kc][cd], o_acc[t][cd], 0, 0, 0);
                }
            }
        }
        __syncthreads();   // drains vmcnt: next-K staged & visible; buffer safe to reuse
        cur ^= 1;
    }

    const size_t slab = (size_t)slot * 16 + nh;
    #pragma unroll
    for (int t = 0; t < 2; ++t)
        if (lg == 0)
            rs_part[slab*128 + wv*32 + t*16 + lr] = rs[t];

    #pragma unroll
    for (int t = 0; t < 2; ++t)
        #pragma unroll
        for (int cd = 0; cd < 4; ++cd)
            #pragma unroll
            for (int r = 0; r < 4; ++r) {
                const int row = wv*32 + t*16 + lg*4 + r;
                O_part[slab*8192 + row*64 + cd*16 + lr] = o_acc[t][cd][r];
            }
}

// Reduce chunk partials per (nh,qt), divide by rowsum, write output.
template<int CHUNK>
__global__ __launch_bounds__(256) void reduce_div_kernel(
    const float* __restrict__ O_part, const float* __restrict__ rs_part,
    float* __restrict__ out)
{
    const int idx = blockIdx.x * 256 + threadIdx.x;
    const int d4 = idx & 15;
    const int l  = (idx >> 4) & (L_SEQ - 1);
    const int nh = idx >> 15;
    const int qt = l >> 7;
    const int row = l & 127;
    int cs = 0;
    for (int q = 0; q < qt; ++q) cs += (2*q + 2 + CHUNK - 1) / CHUNK;
    const int nch = (2*qt + 2 + CHUNK - 1) / CHUNK;

    float4 o = {0.f, 0.f, 0.f, 0.f};
    float rssum = 0.f;
    for (int ci = 0; ci < nch; ++ci) {
        const size_t slab = (size_t)(cs + ci) * 16 + nh;
        const float4 p = *(const float4*)(O_part + slab*8192 + row*64 + d4*4);
        o.x += p.x; o.y += p.y; o.z += p.z; o.w += p.w;
        rssum += rs_part[slab*128 + row];
    }
    const float inv = 1.0f / rssum;
    float4 r;
    r.x = o.x * inv; r.y = o.y * inv; r.z = o.z * inv; r.w = o.w * inv;
    const int n = nh >> 3, h = nh & 7;
    *(float4*)(out + ((size_t)(n*L_SEQ + l))*DMODEL + h*DHEAD + d4*4) = r;
}

extern "C" void kernel_launch(void* const* d_in, const int* in_sizes, int n_in,
                              void* d_out, int out_size, void* d_ws, size_t ws_size,
                              hipStream_t stream) {
    const float* y         = (const float*)d_in[0];
    const float* positions = (const float*)d_in[1];
    const float* Wq        = (const float*)d_in[2];
    const float* Wk        = (const float*)d_in[3];
    const float* Wv        = (const float*)d_in[4];
    const float* coeff     = (const float*)d_in[5];
    const float* pw        = (const float*)d_in[6];
    const float* pb        = (const float*)d_in[7];
    float* out = (float*)d_out;

    const size_t SQK = (size_t)16 * QK_STRIDE;   // shorts (8 MB)
    const size_t SV  = (size_t)16 * V_STRIDE;    // shorts (4 MB)
    const size_t SY  = (size_t)4096 * 512;       // 2M shorts (4 MB)
    const size_t SW  = (size_t)3 * 512 * 512;    // 768K shorts (1.5 MB)
    short* Qh = (short*)d_ws;
    short* Ql = Qh + SQK;
    short* Kh = Ql + SQK;
    short* Kl = Kh + SQK;
    short* Vh = Kl + SQK;
    short* Vl = Vh + SV;
    short* yh = Vl + SV;
    short* yl = yh + SY;
    short* wh = yl + SY;
    short* wl = wh + SW;
    float* O_part = (float*)(wl + SW);
    const size_t base_bytes = (SQK*4 + SV*2 + SY*2 + SW*2) * sizeof(short);
    const size_t per_slot   = (size_t)16 * (8192 + 128) * sizeof(float);

    split_kernel<<<dim3(1408), dim3(256), 0, stream>>>(y, Wq, Wk, Wv, yh, yl, wh, wl);
    prep_kernel<<<dim3(32, 8, 3), dim3(256), 0, stream>>>(
        yh, yl, wh, wl, positions, coeff, pw, pb, Qh, Ql, Kh, Kl, Vh, Vl);

    if (ws_size >= base_bytes + 72 * per_slot) {
        float* rs_part = O_part + (size_t)72 * 16 * 8192;
        attn_kernel<4><<<dim3(72 * 16), dim3(256), 0, stream>>>(
            Qh, Ql, Kh, Kl, Vh, Vl, O_part, rs_part);
        reduce_div_kernel<4><<<dim3(2048), dim3(256), 0, stream>>>(O_part, rs_part, out);
    } else {
        float* rs_part = O_part + (size_t)40 * 16 * 8192;
        attn_kernel<8><<<dim3(40 * 16), dim3(256), 0, stream>>>(
            Qh, Ql, Kh, Kl, Vh, Vl, O_part, rs_part);
        reduce_div_kernel<8><<<dim3(2048), dim3(256), 0, stream>>>(O_part, rs_part, out);
    }
}